// Round 3
// baseline (2242.430 us; speedup 1.0000x reference)
//
#include <hip/hip_runtime.h>
#include <math.h>

#define BB 64
#define SS 128
#define C1 64
#define H1D 64
#define C2 128
#define H2D 32
#define FLAT 131072
#define NCOL 500
#define KCH 256      // split-K chunks in mgemm (deterministic partials)
#define KCSZ 512     // k per chunk  (KCH*KCSZ == FLAT)

// ---------------- conv1 (4x4 s2 p1) + leaky ----------------
__global__ __launch_bounds__(256) void k_conv1(const float* __restrict__ x,
    const float* __restrict__ w, const float* __restrict__ bias,
    float* __restrict__ h1)
{
    int tid = blockIdx.x*256 + threadIdx.x;      // b,oc,oh,ow packed
    int ow = tid & 63, oh = (tid>>6)&63, oc = (tid>>12)&63, b = tid>>18;
    const float* xb = x + (size_t)b*3*SS*SS;
    const float* wb = w + oc*48;                 // uniform per wave -> scalar loads
    float acc = bias[oc];
    int ih0 = oh*2-1, iw0 = ow*2-1;
    #pragma unroll
    for (int ic=0; ic<3; ic++)
      #pragma unroll
      for (int kh=0; kh<4; kh++) {
        int ih = ih0+kh;
        if (ih < 0 || ih >= SS) continue;        // wave-uniform branch
        #pragma unroll
        for (int kw=0; kw<4; kw++) {
          int iw = iw0+kw;
          if (iw < 0 || iw >= SS) continue;      // predicated
          acc = fmaf(xb[(ic*SS+ih)*SS+iw], wb[ic*16+kh*4+kw], acc);
        }
      }
    h1[tid] = acc >= 0.f ? acc : 0.2f*acc;
}

// ---------------- conv2 (4x4 s2 p1), LDS-tiled ----------------
// block: 256 thr = 16x16 spatial tile; 32 out-channels per block
// grid: 64 b * 4 tiles * 4 ocg = 1024
__global__ __launch_bounds__(256) void k_conv2(const float* __restrict__ h1,
    const float* __restrict__ w2, const float* __restrict__ b2,
    float* __restrict__ h2)
{
    int bx = blockIdx.x;
    int ocg = bx & 3;
    int tile = (bx>>2) & 3;
    int b = bx >> 4;
    int tr = (tile>>1)*16, tcc = (tile&1)*16;
    int tx = threadIdx.x & 15, ty = threadIdx.x >> 4;

    __shared__ float tin[8][34][34];

    float acc[32];
    #pragma unroll
    for (int i=0;i<32;i++) acc[i]=0.f;

    int ihb = tr*2 - 1, iwb = tcc*2 - 1;

    for (int icc = 0; icc < 64; icc += 8) {
      for (int idx = threadIdx.x; idx < 8*34*34; idx += 256) {
        int ic  = idx / 1156;
        int rem = idx - ic*1156;
        int r   = rem / 34;
        int c   = rem - r*34;
        int ih = ihb + r, iw = iwb + c;
        float v = 0.f;
        if (ih >= 0 && ih < H1D && iw >= 0 && iw < H1D)
          v = h1[(((size_t)b*C1 + (icc+ic))*H1D + ih)*H1D + iw];
        tin[ic][r][c] = v;
      }
      __syncthreads();
      #pragma unroll
      for (int ic = 0; ic < 8; ic++) {
        float v[16];
        #pragma unroll
        for (int kh=0; kh<4; kh++)
          #pragma unroll
          for (int kw=0; kw<4; kw++)
            v[kh*4+kw] = tin[ic][2*ty+kh][2*tx+kw];
        const float* wp = w2 + ((size_t)(ocg*32)*C1 + (icc+ic))*16; // uniform base
        #pragma unroll
        for (int oc=0; oc<32; oc++) {
          #pragma unroll
          for (int t=0; t<16; t++)
            acc[oc] = fmaf(v[t], wp[(size_t)oc*C1*16 + t], acc[oc]); // scalar weights
        }
      }
      __syncthreads();
    }
    int oh = tr + ty, ow = tcc + tx;
    #pragma unroll
    for (int oc=0; oc<32; oc++) {
      int o = ocg*32 + oc;
      h2[(((size_t)b*C2 + o)*H2D + oh)*H2D + ow] = acc[oc] + b2[o];
    }
}

// ---------------- batchnorm stats (per channel), fp64 accumulate ----------------
__global__ __launch_bounds__(256) void k_bnstats(const float* __restrict__ h2,
    const float* __restrict__ gamma, const float* __restrict__ beta,
    float* __restrict__ stats)
{
    int c = blockIdx.x;     // 0..127
    double s1 = 0.0, s2 = 0.0;
    for (int i = threadIdx.x; i < BB*1024; i += 256) {
      int b = i >> 10, hw = i & 1023;
      double v = (double)h2[((size_t)b*C2 + c)*1024 + hw];
      s1 += v; s2 = fma(v, v, s2);
    }
    __shared__ double r1[256], r2[256];
    r1[threadIdx.x] = s1; r2[threadIdx.x] = s2;
    __syncthreads();
    for (int s = 128; s > 0; s >>= 1) {
      if (threadIdx.x < s) { r1[threadIdx.x] += r1[threadIdx.x+s]; r2[threadIdx.x] += r2[threadIdx.x+s]; }
      __syncthreads();
    }
    if (threadIdx.x == 0) {
      double mean = r1[0] * (1.0/65536.0);
      double var  = r2[0] * (1.0/65536.0) - mean*mean;
      double rstd = 1.0 / sqrt(var + 1e-5);
      double sc = rstd * (double)gamma[c];
      stats[c]      = (float)sc;                           // scale
      stats[C2 + c] = (float)((double)beta[c] - mean*sc);  // shift
    }
}

// ---------------- BN apply + leaky -> feat ----------------
__global__ __launch_bounds__(256) void k_bnapply(const float* __restrict__ h2,
    const float* __restrict__ stats, float* __restrict__ feat)
{
    int i = blockIdx.x*256 + threadIdx.x;       // float4 index
    int c = (i >> 8) & 127;
    float sc = stats[c], sh = stats[C2 + c];
    float4 v = ((const float4*)h2)[i];
    float4 o;
    o.x = fmaf(v.x, sc, sh); o.x = o.x >= 0.f ? o.x : 0.2f*o.x;
    o.y = fmaf(v.y, sc, sh); o.y = o.y >= 0.f ? o.y : 0.2f*o.y;
    o.z = fmaf(v.z, sc, sh); o.z = o.z >= 0.f ? o.z : 0.2f*o.z;
    o.w = fmaf(v.w, sc, sh); o.w = o.w >= 0.f ? o.w : 0.2f*o.w;
    ((float4*)feat)[i] = o;
}

// ---------------- M = feat @ T  (deterministic split-K) ----------------
// wave: lane = column (coalesced T), feat loads wave-uniform (broadcast)
// writes partials [KCH][64][512]
__global__ __launch_bounds__(256) void k_mgemm(const float* __restrict__ feat,
    const float* __restrict__ T, float* __restrict__ Mpart)
{
    int wave = threadIdx.x >> 6, lane = threadIdx.x & 63;
    int cg = blockIdx.x;              // 0..7
    int kc = blockIdx.y*4 + wave;     // 0..KCH-1
    int col = cg*64 + lane;           // 0..511
    bool valid = col < NCOL;
    int k0b = __builtin_amdgcn_readfirstlane(kc * KCSZ);
    float acc[64];
    #pragma unroll
    for (int r=0;r<64;r++) acc[r] = 0.f;
    for (int kk = 0; kk < KCSZ; kk += 8) {
      int k0 = k0b + kk;
      float t[8];
      #pragma unroll
      for (int j=0;j<8;j++)
        t[j] = valid ? T[(size_t)(k0+j)*NCOL + col] : 0.f;
      #pragma unroll 8
      for (int r=0;r<64;r++) {
        const float* fp = feat + (size_t)r*FLAT + k0;   // uniform address
        float4 f0 = *(const float4*)fp;
        float4 f1 = *(const float4*)(fp+4);
        float a = acc[r];
        a = fmaf(f0.x, t[0], a); a = fmaf(f0.y, t[1], a);
        a = fmaf(f0.z, t[2], a); a = fmaf(f0.w, t[3], a);
        a = fmaf(f1.x, t[4], a); a = fmaf(f1.y, t[5], a);
        a = fmaf(f1.z, t[6], a); a = fmaf(f1.w, t[7], a);
        acc[r] = a;
      }
    }
    float* op = Mpart + (size_t)kc*64*512 + col;
    #pragma unroll
    for (int r=0;r<64;r++) op[(size_t)r*512] = acc[r];
}

__global__ __launch_bounds__(256) void k_mreduce(const float* __restrict__ Mpart,
    float* __restrict__ M)
{
    int i = blockIdx.x*256 + threadIdx.x;   // 32000 = 64*500
    int r = i / NCOL, c = i - r*NCOL;
    float s = 0.f;
    const float* p = Mpart + (size_t)r*512 + c;
    #pragma unroll 8
    for (int kc = 0; kc < KCH; kc++) s += p[(size_t)kc*64*512];
    M[i] = s;
}

// ---------------- minibatch discrimination: o_b ----------------
__global__ __launch_bounds__(256) void k_ob(const float* __restrict__ M,
    float* __restrict__ ob)
{
    int o = blockIdx.x;   // 0..99
    __shared__ float Ms[320];
    __shared__ float red[256];
    // 320 entries, 256 threads -> strided loop (BUG FIX: entries 256..319 were
    // previously never written -> uninitialized LDS -> nondeterminism/NaN)
    for (int idx = threadIdx.x; idx < 320; idx += 256) {
      int a = idx / 5, d = idx - a*5;
      Ms[idx] = M[(size_t)a*NCOL + o*5 + d];
    }
    __syncthreads();
    int b = threadIdx.x & 63, aq = threadIdx.x >> 6;
    float s = 0.f;
    for (int a = aq*16; a < aq*16+16; a++) {
      float n = 0.f;
      #pragma unroll
      for (int d=0; d<5; d++) n += fabsf(Ms[a*5+d] - Ms[b*5+d]);
      s += expf(-n);
    }
    red[threadIdx.x] = s;
    __syncthreads();
    if (threadIdx.x < 64)
      ob[(size_t)b*100 + o] = red[b] + red[64+b] + red[128+b] + red[192+b];
}

// ---------------- final linear + sigmoid (fp64 accumulate) ----------------
__global__ __launch_bounds__(256) void k_final(const float* __restrict__ feat,
    const float* __restrict__ ob, const float* __restrict__ lw,
    const float* __restrict__ lb, float* __restrict__ out)
{
    int b = blockIdx.x;
    const float4* fp = (const float4*)(feat + (size_t)b*FLAT);
    const float4* wp = (const float4*)lw;
    double s = 0.0;
    for (int j = threadIdx.x; j < FLAT/4; j += 256) {
      float4 f = fp[j], w = wp[j];
      s = fma((double)f.x, (double)w.x, s);
      s = fma((double)f.y, (double)w.y, s);
      s = fma((double)f.z, (double)w.z, s);
      s = fma((double)f.w, (double)w.w, s);
    }
    if (threadIdx.x < 100)
      s = fma((double)ob[(size_t)b*100 + threadIdx.x], (double)lw[FLAT + threadIdx.x], s);
    __shared__ double red[256];
    red[threadIdx.x] = s;
    __syncthreads();
    for (int st = 128; st > 0; st >>= 1) {
      if (threadIdx.x < st) red[threadIdx.x] += red[threadIdx.x + st];
      __syncthreads();
    }
    if (threadIdx.x == 0) {
      double logit = red[0] + (double)lb[0];
      out[b] = (float)(1.0 / (1.0 + exp(-logit)));
    }
}

extern "C" void kernel_launch(void* const* d_in, const int* in_sizes, int n_in,
                              void* d_out, int out_size, void* d_ws, size_t ws_size,
                              hipStream_t stream)
{
    const float* x   = (const float*)d_in[0];
    const float* w1  = (const float*)d_in[1];
    const float* b1  = (const float*)d_in[2];
    const float* w2  = (const float*)d_in[3];
    const float* b2  = (const float*)d_in[4];
    const float* gam = (const float*)d_in[5];
    const float* bet = (const float*)d_in[6];
    const float* T   = (const float*)d_in[7];
    const float* lw  = (const float*)d_in[8];
    const float* lb  = (const float*)d_in[9];
    float* out = (float*)d_out;

    float* ws = (float*)d_ws;
    // Layout (floats):
    //   [0 .. 16,777,216)           h1   (dead after conv2)
    //     after conv2:
    //   [0 .. 8,388,608)            feat (aliases h1 lo half)
    //   [8,388,608 .. 16,777,216)   Mpart = [KCH=256][64][512] (aliases h1 hi half)
    //   [16,777,216 .. 25,165,824)  h2
    //   [25,165,824 .. +32000)      M
    //   then stats(256), ob(6400)
    // Total = 25,204,480 floats = 100.82 MB.
    float* h1    = ws;
    float* feat  = ws;
    float* Mpart = ws + 8388608;
    float* h2    = ws + 16777216;
    float* M     = ws + 25165824;
    float* stats = M + 32000;
    float* ob    = stats + 256;

    k_conv1<<<65536, 256, 0, stream>>>(x, w1, b1, h1);
    k_conv2<<<1024, 256, 0, stream>>>(h1, w2, b2, h2);
    k_bnstats<<<128, 256, 0, stream>>>(h2, gam, bet, stats);
    k_bnapply<<<8192, 256, 0, stream>>>(h2, stats, feat);
    k_mgemm<<<dim3(8, KCH/4), 256, 0, stream>>>(feat, T, Mpart);
    k_mreduce<<<125, 256, 0, stream>>>(Mpart, M);
    k_ob<<<100, 256, 0, stream>>>(M, ob);
    k_final<<<64, 256, 0, stream>>>(feat, ob, lw, lb, out);
}

// Round 4
// 1683.361 us; speedup vs baseline: 1.3321x; 1.3321x over previous
//
#include <hip/hip_runtime.h>
#include <math.h>

#define BB 64
#define SS 128
#define C1 64
#define H1D 64
#define C2 128
#define H2D 32
#define FLAT 131072
#define NCOL 500
#define KCH 256      // split-K chunks in mgemm (deterministic partials)
#define KCSZ 512     // k per chunk  (KCH*KCSZ == FLAT)

// ---------------- conv1 (4x4 s2 p1) + leaky ----------------
__global__ __launch_bounds__(256) void k_conv1(const float* __restrict__ x,
    const float* __restrict__ w, const float* __restrict__ bias,
    float* __restrict__ h1)
{
    int tid = blockIdx.x*256 + threadIdx.x;      // b,oc,oh,ow packed
    int ow = tid & 63, oh = (tid>>6)&63, oc = (tid>>12)&63, b = tid>>18;
    const float* xb = x + (size_t)b*3*SS*SS;
    const float* wb = w + oc*48;                 // uniform per wave -> scalar loads
    float acc = bias[oc];
    int ih0 = oh*2-1, iw0 = ow*2-1;
    #pragma unroll
    for (int ic=0; ic<3; ic++)
      #pragma unroll
      for (int kh=0; kh<4; kh++) {
        int ih = ih0+kh;
        if (ih < 0 || ih >= SS) continue;        // wave-uniform branch
        #pragma unroll
        for (int kw=0; kw<4; kw++) {
          int iw = iw0+kw;
          if (iw < 0 || iw >= SS) continue;      // predicated
          acc = fmaf(xb[(ic*SS+ih)*SS+iw], wb[ic*16+kh*4+kw], acc);
        }
      }
    h1[tid] = acc >= 0.f ? acc : 0.2f*acc;
}

// ---------------- conv2 (4x4 s2 p1), LDS-tiled ----------------
// block: 256 thr = 16x16 spatial tile; 32 out-channels per block
// grid: 64 b * 4 tiles * 4 ocg = 1024
__global__ __launch_bounds__(256) void k_conv2(const float* __restrict__ h1,
    const float* __restrict__ w2, const float* __restrict__ b2,
    float* __restrict__ h2)
{
    int bx = blockIdx.x;
    int ocg = bx & 3;
    int tile = (bx>>2) & 3;
    int b = bx >> 4;
    int tr = (tile>>1)*16, tcc = (tile&1)*16;
    int tx = threadIdx.x & 15, ty = threadIdx.x >> 4;

    __shared__ float tin[8][34][34];

    float acc[32];
    #pragma unroll
    for (int i=0;i<32;i++) acc[i]=0.f;

    int ihb = tr*2 - 1, iwb = tcc*2 - 1;

    for (int icc = 0; icc < 64; icc += 8) {
      for (int idx = threadIdx.x; idx < 8*34*34; idx += 256) {
        int ic  = idx / 1156;
        int rem = idx - ic*1156;
        int r   = rem / 34;
        int c   = rem - r*34;
        int ih = ihb + r, iw = iwb + c;
        float v = 0.f;
        if (ih >= 0 && ih < H1D && iw >= 0 && iw < H1D)
          v = h1[(((size_t)b*C1 + (icc+ic))*H1D + ih)*H1D + iw];
        tin[ic][r][c] = v;
      }
      __syncthreads();
      #pragma unroll
      for (int ic = 0; ic < 8; ic++) {
        float v[16];
        #pragma unroll
        for (int kh=0; kh<4; kh++)
          #pragma unroll
          for (int kw=0; kw<4; kw++)
            v[kh*4+kw] = tin[ic][2*ty+kh][2*tx+kw];
        const float* wp = w2 + ((size_t)(ocg*32)*C1 + (icc+ic))*16; // uniform base
        #pragma unroll
        for (int oc=0; oc<32; oc++) {
          #pragma unroll
          for (int t=0; t<16; t++)
            acc[oc] = fmaf(v[t], wp[(size_t)oc*C1*16 + t], acc[oc]); // scalar weights
        }
      }
      __syncthreads();
    }
    int oh = tr + ty, ow = tcc + tx;
    #pragma unroll
    for (int oc=0; oc<32; oc++) {
      int o = ocg*32 + oc;
      h2[(((size_t)b*C2 + o)*H2D + oh)*H2D + ow] = acc[oc] + b2[o];
    }
}

// ---------------- batchnorm stats (per channel), fp64 accumulate ----------------
__global__ __launch_bounds__(256) void k_bnstats(const float* __restrict__ h2,
    const float* __restrict__ gamma, const float* __restrict__ beta,
    float* __restrict__ stats)
{
    int c = blockIdx.x;     // 0..127
    double s1 = 0.0, s2 = 0.0;
    for (int i = threadIdx.x; i < BB*1024; i += 256) {
      int b = i >> 10, hw = i & 1023;
      double v = (double)h2[((size_t)b*C2 + c)*1024 + hw];
      s1 += v; s2 = fma(v, v, s2);
    }
    __shared__ double r1[256], r2[256];
    r1[threadIdx.x] = s1; r2[threadIdx.x] = s2;
    __syncthreads();
    for (int s = 128; s > 0; s >>= 1) {
      if (threadIdx.x < s) { r1[threadIdx.x] += r1[threadIdx.x+s]; r2[threadIdx.x] += r2[threadIdx.x+s]; }
      __syncthreads();
    }
    if (threadIdx.x == 0) {
      double mean = r1[0] * (1.0/65536.0);
      double var  = r2[0] * (1.0/65536.0) - mean*mean;
      double rstd = 1.0 / sqrt(var + 1e-5);
      double sc = rstd * (double)gamma[c];
      stats[c]      = (float)sc;                           // scale
      stats[C2 + c] = (float)((double)beta[c] - mean*sc);  // shift
    }
}

// ---------------- BN apply + leaky -> feat ----------------
__global__ __launch_bounds__(256) void k_bnapply(const float* __restrict__ h2,
    const float* __restrict__ stats, float* __restrict__ feat)
{
    int i = blockIdx.x*256 + threadIdx.x;       // float4 index
    int c = (i >> 8) & 127;
    float sc = stats[c], sh = stats[C2 + c];
    float4 v = ((const float4*)h2)[i];
    float4 o;
    o.x = fmaf(v.x, sc, sh); o.x = o.x >= 0.f ? o.x : 0.2f*o.x;
    o.y = fmaf(v.y, sc, sh); o.y = o.y >= 0.f ? o.y : 0.2f*o.y;
    o.z = fmaf(v.z, sc, sh); o.z = o.z >= 0.f ? o.z : 0.2f*o.z;
    o.w = fmaf(v.w, sc, sh); o.w = o.w >= 0.f ? o.w : 0.2f*o.w;
    ((float4*)feat)[i] = o;
}

// ---------------- M = feat @ T  (deterministic split-K) ----------------
// wave: lane = column (coalesced T), feat loads wave-uniform (broadcast)
// writes partials [KCH][64][512]
// NOTE: r-loop must be FULLY unrolled -> acc[] indices compile-time constant
// (partial unroll made acc runtime-indexed -> scratch spill -> 10x slowdown)
__global__ __launch_bounds__(256) void k_mgemm(const float* __restrict__ feat,
    const float* __restrict__ T, float* __restrict__ Mpart)
{
    int wave = threadIdx.x >> 6, lane = threadIdx.x & 63;
    int cg = blockIdx.x;              // 0..7
    int kc = blockIdx.y*4 + wave;     // 0..KCH-1
    int col = cg*64 + lane;           // 0..511
    bool valid = col < NCOL;
    int k0b = __builtin_amdgcn_readfirstlane(kc * KCSZ);
    float acc[64];
    #pragma unroll
    for (int r=0;r<64;r++) acc[r] = 0.f;
    for (int kk = 0; kk < KCSZ; kk += 8) {
      int k0 = k0b + kk;
      float t[8];
      #pragma unroll
      for (int j=0;j<8;j++)
        t[j] = valid ? T[(size_t)(k0+j)*NCOL + col] : 0.f;
      #pragma unroll
      for (int r=0;r<64;r++) {
        const float4* fp = (const float4*)(feat + (size_t)r*FLAT + k0); // uniform
        float4 f0 = fp[0];
        float4 f1 = fp[1];
        float a = acc[r];
        a = fmaf(f0.x, t[0], a); a = fmaf(f0.y, t[1], a);
        a = fmaf(f0.z, t[2], a); a = fmaf(f0.w, t[3], a);
        a = fmaf(f1.x, t[4], a); a = fmaf(f1.y, t[5], a);
        a = fmaf(f1.z, t[6], a); a = fmaf(f1.w, t[7], a);
        acc[r] = a;
      }
    }
    float* op = Mpart + (size_t)kc*64*512 + col;
    #pragma unroll
    for (int r=0;r<64;r++) op[(size_t)r*512] = acc[r];
}

__global__ __launch_bounds__(256) void k_mreduce(const float* __restrict__ Mpart,
    float* __restrict__ M)
{
    int i = blockIdx.x*256 + threadIdx.x;   // 32000 = 64*500
    int r = i / NCOL, c = i - r*NCOL;
    float s = 0.f;
    const float* p = Mpart + (size_t)r*512 + c;
    #pragma unroll 8
    for (int kc = 0; kc < KCH; kc++) s += p[(size_t)kc*64*512];
    M[i] = s;
}

// ---------------- minibatch discrimination: o_b ----------------
__global__ __launch_bounds__(256) void k_ob(const float* __restrict__ M,
    float* __restrict__ ob)
{
    int o = blockIdx.x;   // 0..99
    __shared__ float Ms[320];
    __shared__ float red[256];
    for (int idx = threadIdx.x; idx < 320; idx += 256) {
      int a = idx / 5, d = idx - a*5;
      Ms[idx] = M[(size_t)a*NCOL + o*5 + d];
    }
    __syncthreads();
    int b = threadIdx.x & 63, aq = threadIdx.x >> 6;
    float s = 0.f;
    for (int a = aq*16; a < aq*16+16; a++) {
      float n = 0.f;
      #pragma unroll
      for (int d=0; d<5; d++) n += fabsf(Ms[a*5+d] - Ms[b*5+d]);
      s += expf(-n);
    }
    red[threadIdx.x] = s;
    __syncthreads();
    if (threadIdx.x < 64)
      ob[(size_t)b*100 + o] = red[b] + red[64+b] + red[128+b] + red[192+b];
}

// ---------------- final linear + sigmoid (fp64 accumulate) ----------------
__global__ __launch_bounds__(256) void k_final(const float* __restrict__ feat,
    const float* __restrict__ ob, const float* __restrict__ lw,
    const float* __restrict__ lb, float* __restrict__ out)
{
    int b = blockIdx.x;
    const float4* fp = (const float4*)(feat + (size_t)b*FLAT);
    const float4* wp = (const float4*)lw;
    double s = 0.0;
    for (int j = threadIdx.x; j < FLAT/4; j += 256) {
      float4 f = fp[j], w = wp[j];
      s = fma((double)f.x, (double)w.x, s);
      s = fma((double)f.y, (double)w.y, s);
      s = fma((double)f.z, (double)w.z, s);
      s = fma((double)f.w, (double)w.w, s);
    }
    if (threadIdx.x < 100)
      s = fma((double)ob[(size_t)b*100 + threadIdx.x], (double)lw[FLAT + threadIdx.x], s);
    __shared__ double red[256];
    red[threadIdx.x] = s;
    __syncthreads();
    for (int st = 128; st > 0; st >>= 1) {
      if (threadIdx.x < st) red[threadIdx.x] += red[threadIdx.x + st];
      __syncthreads();
    }
    if (threadIdx.x == 0) {
      double logit = red[0] + (double)lb[0];
      out[b] = (float)(1.0 / (1.0 + exp(-logit)));
    }
}

extern "C" void kernel_launch(void* const* d_in, const int* in_sizes, int n_in,
                              void* d_out, int out_size, void* d_ws, size_t ws_size,
                              hipStream_t stream)
{
    const float* x   = (const float*)d_in[0];
    const float* w1  = (const float*)d_in[1];
    const float* b1  = (const float*)d_in[2];
    const float* w2  = (const float*)d_in[3];
    const float* b2  = (const float*)d_in[4];
    const float* gam = (const float*)d_in[5];
    const float* bet = (const float*)d_in[6];
    const float* T   = (const float*)d_in[7];
    const float* lw  = (const float*)d_in[8];
    const float* lb  = (const float*)d_in[9];
    float* out = (float*)d_out;

    float* ws = (float*)d_ws;
    // Layout (floats), total 25,204,480 floats = 100.82 MB:
    //   [0 .. 16,777,216)           h1   (dead after conv2)
    //     after conv2: feat = lo half, Mpart = hi half
    //   [16,777,216 .. 25,165,824)  h2
    //   [25,165,824 ..)             M(32000), stats(256), ob(6400)
    float* h1    = ws;
    float* feat  = ws;
    float* Mpart = ws + 8388608;
    float* h2    = ws + 16777216;
    float* M     = ws + 25165824;
    float* stats = M + 32000;
    float* ob    = stats + 256;

    k_conv1<<<65536, 256, 0, stream>>>(x, w1, b1, h1);
    k_conv2<<<1024, 256, 0, stream>>>(h1, w2, b2, h2);
    k_bnstats<<<128, 256, 0, stream>>>(h2, gam, bet, stats);
    k_bnapply<<<8192, 256, 0, stream>>>(h2, stats, feat);
    k_mgemm<<<dim3(8, KCH/4), 256, 0, stream>>>(feat, T, Mpart);
    k_mreduce<<<125, 256, 0, stream>>>(Mpart, M);
    k_ob<<<100, 256, 0, stream>>>(M, ob);
    k_final<<<64, 256, 0, stream>>>(feat, ob, lw, lb, out);
}

// Round 5
// 787.809 us; speedup vs baseline: 2.8464x; 2.1368x over previous
//
#include <hip/hip_runtime.h>
#include <hip/hip_bf16.h>
#include <math.h>

#define BB 64
#define SS 128
#define C1 64
#define H1D 64
#define C2 128
#define H2D 32
#define FLAT 131072
#define NCOL 500
#define KCH 256      // split-K chunks in mgemm (deterministic partials)
#define KCSZ 512     // k per chunk  (KCH*KCSZ == FLAT)

typedef __attribute__((ext_vector_type(4))) float f32x4;
typedef __attribute__((ext_vector_type(8))) short bf16x8;

// ---------------- conv1 (4x4 s2 p1) + leaky -> h1 bf16 [g4][b][oh][ow][16ic] ----------------
__global__ __launch_bounds__(256) void k_conv1(const float* __restrict__ x,
    const float* __restrict__ w, const float* __restrict__ bias,
    __hip_bfloat16* __restrict__ h1)
{
    int tid = blockIdx.x*256 + threadIdx.x;      // (b, oh, ow)
    int ow = tid & 63, oh = (tid>>6)&63, bi = tid>>12;
    int ih0 = oh*2-1, iw0 = ow*2-1;
    float in[48];
    #pragma unroll
    for (int ic=0; ic<3; ic++)
      #pragma unroll
      for (int kh=0; kh<4; kh++)
        #pragma unroll
        for (int kw=0; kw<4; kw++) {
          int ih = ih0+kh, iw = iw0+kw;
          float v = 0.f;
          if ((unsigned)ih < 128u && (unsigned)iw < 128u)
            v = x[((size_t)(bi*3+ic)*SS + ih)*SS + iw];
          in[ic*16+kh*4+kw] = v;
        }
    #pragma unroll
    for (int g=0; g<4; g++) {
      __hip_bfloat16 outv[16];
      #pragma unroll
      for (int ocl=0; ocl<16; ocl++) {
        int oc = g*16 + ocl;
        float a = bias[oc];
        const float* wp = w + oc*48;             // wave-uniform -> scalar loads
        #pragma unroll
        for (int t=0; t<48; t++) a = fmaf(in[t], wp[t], a);
        a = a >= 0.f ? a : 0.2f*a;
        outv[ocl] = __float2bfloat16(a);
      }
      __hip_bfloat16* dst = h1 + (((size_t)g*BB + bi)*4096 + oh*64 + ow)*16;
      *(bf16x8*)(dst)     = *(bf16x8*)&outv[0];
      *(bf16x8*)(dst + 8) = *(bf16x8*)&outv[8];
    }
}

// ---------------- weight prep: w2 fp32 -> Bw bf16 [stage4][kl8 32][oc 128][jj 8] ----------------
__global__ __launch_bounds__(256) void k_prepw(const float* __restrict__ w2,
    __hip_bfloat16* __restrict__ Bw)
{
    int i = blockIdx.x*256 + threadIdx.x;        // 131072
    int jj = i & 7, oc = (i>>3)&127, kl8 = (i>>10)&31, stage = i>>15;
    int kl = kl8*8 + jj;                         // k-local within stage: tap*16 + icl
    int tap = kl >> 4, icl = kl & 15;
    int ic = stage*16 + icl;
    Bw[i] = __float2bfloat16(w2[(size_t)oc*1024 + ic*16 + tap]);
}

// ---------------- conv2 via MFMA bf16 implicit GEMM ----------------
// grid 512: blockIdx = b*8 + strip*2 + nh.  Block: 256 thr = 4 waves.
// M-tile = 256 px (8 oh rows x 32 ow) of batch b; N = 64 oc (half nh).
// K = 1024 = 4 stages x (16 ic x 16 taps).  LDS: A-tile, 48B-pitch rows.
__global__ __launch_bounds__(256) void k_conv2(const __hip_bfloat16* __restrict__ h1,
    const __hip_bfloat16* __restrict__ Bw, const float* __restrict__ b2,
    float* __restrict__ h2)
{
    int bx = blockIdx.x;
    int nh = bx & 1, strip = (bx>>1)&3, bi = bx>>3;
    int lane = threadIdx.x & 63, wv = threadIdx.x >> 6;
    int l15 = lane & 15, kg = lane >> 4;

    __shared__ __align__(16) short tile[36*33*24];   // 1188 rows x 48B = 57 KB

    f32x4 acc[4][4];
    #pragma unroll
    for (int m=0;m<4;m++)
      #pragma unroll
      for (int n=0;n<4;n++) acc[m][n] = (f32x4)(0.f);

    int ihb = strip*16 - 1;                      // global ih of ih_l=0

    for (int stage=0; stage<4; ++stage) {
      const __hip_bfloat16* hsrc = h1 + ((size_t)stage*BB + bi)*4096*16;
      for (int idx = threadIdx.x; idx < 2376; idx += 256) {
        int half = idx & 1, p = idx >> 1;        // p = ih_l*66 + iw_l
        int ih_l = p / 66, iw_l = p - ih_l*66;
        int ih = ihb + ih_l, iw = iw_l - 1;
        int row48 = (ih_l*2 + (iw_l&1))*33 + (iw_l>>1);
        bf16x8 v = (bf16x8)(0);
        if ((unsigned)ih < 64u && (unsigned)iw < 64u)
          v = *(const bf16x8*)(hsrc + ((size_t)(ih*64+iw)*16 + half*8));
        *(bf16x8*)&tile[row48*24 + half*8] = v;
      }
      __syncthreads();
      const __hip_bfloat16* bwst = Bw + (size_t)stage*32*128*8;
      #pragma unroll
      for (int j=0; j<8; j++) {
        bf16x8 bf[4];
        #pragma unroll
        for (int nf=0; nf<4; nf++)
          bf[nf] = *(const bf16x8*)(bwst + ((size_t)((j*4+kg)*128) + nh*64 + nf*16 + l15)*8);
        int tap = 2*j + (kg>>1);
        int kh = tap>>2, kw = tap&3;
        int icl0 = (kg&1)*8;
        bf16x8 af[4];
        #pragma unroll
        for (int mf=0; mf<4; mf++) {
          int oh_l = 2*wv + (mf>>1);
          int ow   = (mf&1)*16 + l15;
          int ih_l = 2*oh_l + kh;
          int iw_l = 2*ow + kw;
          int row48 = (ih_l*2 + (iw_l&1))*33 + (iw_l>>1);
          af[mf] = *(const bf16x8*)&tile[row48*24 + icl0];
        }
        #pragma unroll
        for (int mf=0; mf<4; mf++)
          #pragma unroll
          for (int nf=0; nf<4; nf++)
            acc[mf][nf] = __builtin_amdgcn_mfma_f32_16x16x32_bf16(af[mf], bf[nf], acc[mf][nf], 0, 0, 0);
      }
      __syncthreads();
    }
    // epilogue: D row = pixel = wv*64 + mf*16 + kg*4 + j ; col = oc = nh*64 + nf*16 + l15
    #pragma unroll
    for (int mf=0; mf<4; mf++)
      #pragma unroll
      for (int nf=0; nf<4; nf++) {
        int oc = nh*64 + nf*16 + l15;
        int p0 = wv*64 + mf*16 + kg*4;
        float bv = b2[oc];
        float4 o;
        o.x = acc[mf][nf][0] + bv;
        o.y = acc[mf][nf][1] + bv;
        o.z = acc[mf][nf][2] + bv;
        o.w = acc[mf][nf][3] + bv;
        *(float4*)&h2[((size_t)bi*C2 + oc)*1024 + strip*256 + p0] = o;
      }
}

// ---------------- batchnorm stats (per channel), fp64 accumulate ----------------
__global__ __launch_bounds__(256) void k_bnstats(const float* __restrict__ h2,
    const float* __restrict__ gamma, const float* __restrict__ beta,
    float* __restrict__ stats)
{
    int c = blockIdx.x;     // 0..127
    double s1 = 0.0, s2 = 0.0;
    for (int i = threadIdx.x; i < BB*1024; i += 256) {
      int b = i >> 10, hw = i & 1023;
      double v = (double)h2[((size_t)b*C2 + c)*1024 + hw];
      s1 += v; s2 = fma(v, v, s2);
    }
    __shared__ double r1[256], r2[256];
    r1[threadIdx.x] = s1; r2[threadIdx.x] = s2;
    __syncthreads();
    for (int s = 128; s > 0; s >>= 1) {
      if (threadIdx.x < s) { r1[threadIdx.x] += r1[threadIdx.x+s]; r2[threadIdx.x] += r2[threadIdx.x+s]; }
      __syncthreads();
    }
    if (threadIdx.x == 0) {
      double mean = r1[0] * (1.0/65536.0);
      double var  = r2[0] * (1.0/65536.0) - mean*mean;
      double rstd = 1.0 / sqrt(var + 1e-5);
      double sc = rstd * (double)gamma[c];
      stats[c]      = (float)sc;                           // scale
      stats[C2 + c] = (float)((double)beta[c] - mean*sc);  // shift
    }
}

// ---------------- BN apply + leaky (IN-PLACE h2 -> feat) ----------------
__global__ __launch_bounds__(256) void k_bnapply(float* __restrict__ h2,
    const float* __restrict__ stats)
{
    int i = blockIdx.x*256 + threadIdx.x;       // float4 index
    int c = (i >> 8) & 127;
    float sc = stats[c], sh = stats[C2 + c];
    float4 v = ((const float4*)h2)[i];
    float4 o;
    o.x = fmaf(v.x, sc, sh); o.x = o.x >= 0.f ? o.x : 0.2f*o.x;
    o.y = fmaf(v.y, sc, sh); o.y = o.y >= 0.f ? o.y : 0.2f*o.y;
    o.z = fmaf(v.z, sc, sh); o.z = o.z >= 0.f ? o.z : 0.2f*o.z;
    o.w = fmaf(v.w, sc, sh); o.w = o.w >= 0.f ? o.w : 0.2f*o.w;
    ((float4*)h2)[i] = o;
}

// ---------------- M = feat @ T  (deterministic split-K) ----------------
__global__ __launch_bounds__(256) void k_mgemm(const float* __restrict__ feat,
    const float* __restrict__ T, float* __restrict__ Mpart)
{
    int wave = threadIdx.x >> 6, lane = threadIdx.x & 63;
    int cg = blockIdx.x;              // 0..7
    int kc = blockIdx.y*4 + wave;     // 0..KCH-1
    int col = cg*64 + lane;           // 0..511
    bool valid = col < NCOL;
    int k0b = __builtin_amdgcn_readfirstlane(kc * KCSZ);
    float acc[64];
    #pragma unroll
    for (int r=0;r<64;r++) acc[r] = 0.f;
    for (int kk = 0; kk < KCSZ; kk += 8) {
      int k0 = k0b + kk;
      float t[8];
      #pragma unroll
      for (int j=0;j<8;j++)
        t[j] = valid ? T[(size_t)(k0+j)*NCOL + col] : 0.f;
      #pragma unroll
      for (int r=0;r<64;r++) {
        const float4* fp = (const float4*)(feat + (size_t)r*FLAT + k0); // uniform
        float4 f0 = fp[0];
        float4 f1 = fp[1];
        float a = acc[r];
        a = fmaf(f0.x, t[0], a); a = fmaf(f0.y, t[1], a);
        a = fmaf(f0.z, t[2], a); a = fmaf(f0.w, t[3], a);
        a = fmaf(f1.x, t[4], a); a = fmaf(f1.y, t[5], a);
        a = fmaf(f1.z, t[6], a); a = fmaf(f1.w, t[7], a);
        acc[r] = a;
      }
    }
    float* op = Mpart + (size_t)kc*64*512 + col;
    #pragma unroll
    for (int r=0;r<64;r++) op[(size_t)r*512] = acc[r];
}

__global__ __launch_bounds__(256) void k_mreduce(const float* __restrict__ Mpart,
    float* __restrict__ M)
{
    int i = blockIdx.x*256 + threadIdx.x;   // 32000 = 64*500
    int r = i / NCOL, c = i - r*NCOL;
    float s = 0.f;
    const float* p = Mpart + (size_t)r*512 + c;
    #pragma unroll 8
    for (int kc = 0; kc < KCH; kc++) s += p[(size_t)kc*64*512];
    M[i] = s;
}

// ---------------- minibatch discrimination: o_b ----------------
__global__ __launch_bounds__(256) void k_ob(const float* __restrict__ M,
    float* __restrict__ ob)
{
    int o = blockIdx.x;   // 0..99
    __shared__ float Ms[320];
    __shared__ float red[256];
    for (int idx = threadIdx.x; idx < 320; idx += 256) {
      int a = idx / 5, d = idx - a*5;
      Ms[idx] = M[(size_t)a*NCOL + o*5 + d];
    }
    __syncthreads();
    int b = threadIdx.x & 63, aq = threadIdx.x >> 6;
    float s = 0.f;
    for (int a = aq*16; a < aq*16+16; a++) {
      float n = 0.f;
      #pragma unroll
      for (int d=0; d<5; d++) n += fabsf(Ms[a*5+d] - Ms[b*5+d]);
      s += expf(-n);
    }
    red[threadIdx.x] = s;
    __syncthreads();
    if (threadIdx.x < 64)
      ob[(size_t)b*100 + o] = red[b] + red[64+b] + red[128+b] + red[192+b];
}

// ---------------- final linear + sigmoid (fp64 accumulate) ----------------
__global__ __launch_bounds__(256) void k_final(const float* __restrict__ feat,
    const float* __restrict__ ob, const float* __restrict__ lw,
    const float* __restrict__ lb, float* __restrict__ out)
{
    int b = blockIdx.x;
    const float4* fp = (const float4*)(feat + (size_t)b*FLAT);
    const float4* wp = (const float4*)lw;
    double s = 0.0;
    for (int j = threadIdx.x; j < FLAT/4; j += 256) {
      float4 f = fp[j], w = wp[j];
      s = fma((double)f.x, (double)w.x, s);
      s = fma((double)f.y, (double)w.y, s);
      s = fma((double)f.z, (double)w.z, s);
      s = fma((double)f.w, (double)w.w, s);
    }
    if (threadIdx.x < 100)
      s = fma((double)ob[(size_t)b*100 + threadIdx.x], (double)lw[FLAT + threadIdx.x], s);
    __shared__ double red[256];
    red[threadIdx.x] = s;
    __syncthreads();
    for (int st = 128; st > 0; st >>= 1) {
      if (threadIdx.x < st) red[threadIdx.x] += red[threadIdx.x + st];
      __syncthreads();
    }
    if (threadIdx.x == 0) {
      double logit = red[0] + (double)lb[0];
      out[b] = (float)(1.0 / (1.0 + exp(-logit)));
    }
}

extern "C" void kernel_launch(void* const* d_in, const int* in_sizes, int n_in,
                              void* d_out, int out_size, void* d_ws, size_t ws_size,
                              hipStream_t stream)
{
    const float* x   = (const float*)d_in[0];
    const float* w1  = (const float*)d_in[1];
    const float* b1  = (const float*)d_in[2];
    const float* w2  = (const float*)d_in[3];
    const float* b2  = (const float*)d_in[4];
    const float* gam = (const float*)d_in[5];
    const float* bet = (const float*)d_in[6];
    const float* T   = (const float*)d_in[7];
    const float* lw  = (const float*)d_in[8];
    const float* lb  = (const float*)d_in[9];
    float* out = (float*)d_out;

    float* ws = (float*)d_ws;
    // Layout (bytes):
    //   [0, 33.5M)      h1 bf16 [4][64][4096][16]   -> later Mpart fp32 [256][64][512]
    //   [33.5M, 67.1M)  h2 fp32 (bnapply in-place -> feat)
    //   [67.1M, ...)    Bw bf16 (256KB) | M (128KB) | stats (1KB) | ob (25.6KB)
    // Total ~67.5 MB (proven ws >= ~100.8 MB).
    __hip_bfloat16* h1 = (__hip_bfloat16*)ws;
    float* Mpart = ws;                               // aliases h1 (dead after conv2)
    float* h2    = ws + 8388608;
    float* feat  = h2;                               // in-place BN
    __hip_bfloat16* Bw = (__hip_bfloat16*)(ws + 16777216);
    float* M     = ws + 16777216 + 65536;
    float* stats = M + 32000;
    float* ob    = stats + 256;

    k_prepw<<<512, 256, 0, stream>>>(w2, Bw);
    k_conv1<<<1024, 256, 0, stream>>>(x, w1, b1, h1);
    k_conv2<<<512, 256, 0, stream>>>(h1, Bw, b2, h2);
    k_bnstats<<<128, 256, 0, stream>>>(h2, gam, bet, stats);
    k_bnapply<<<8192, 256, 0, stream>>>(h2, stats);
    k_mgemm<<<dim3(8, KCH/4), 256, 0, stream>>>(feat, T, Mpart);
    k_mreduce<<<125, 256, 0, stream>>>(Mpart, M);
    k_ob<<<100, 256, 0, stream>>>(M, ob);
    k_final<<<64, 256, 0, stream>>>(feat, ob, lw, lb, out);
}

// Round 6
// 395.482 us; speedup vs baseline: 5.6701x; 1.9920x over previous
//
#include <hip/hip_runtime.h>
#include <hip/hip_bf16.h>
#include <math.h>

#define BB 64
#define SS 128
#define C1 64
#define H1D 64
#define C2 128
#define H2D 32
#define FLAT 131072
#define NCOL 500
#define KCH 256      // split-K chunks in mgemm (deterministic partials)
#define KCSZ 512     // k per chunk  (KCH*KCSZ == FLAT)

typedef __attribute__((ext_vector_type(4))) float f32x4;
typedef __attribute__((ext_vector_type(8))) short bf16x8;

// ---------------- conv1 (4x4 s2 p1) + leaky -> h1 bf16 [g4][b][oh][ow][16ic] ----------------
__global__ __launch_bounds__(256) void k_conv1(const float* __restrict__ x,
    const float* __restrict__ w, const float* __restrict__ bias,
    __hip_bfloat16* __restrict__ h1)
{
    int tid = blockIdx.x*256 + threadIdx.x;      // (b, oh, ow)
    int ow = tid & 63, oh = (tid>>6)&63, bi = tid>>12;
    int ih0 = oh*2-1, iw0 = ow*2-1;
    float in[48];
    #pragma unroll
    for (int ic=0; ic<3; ic++)
      #pragma unroll
      for (int kh=0; kh<4; kh++)
        #pragma unroll
        for (int kw=0; kw<4; kw++) {
          int ih = ih0+kh, iw = iw0+kw;
          float v = 0.f;
          if ((unsigned)ih < 128u && (unsigned)iw < 128u)
            v = x[((size_t)(bi*3+ic)*SS + ih)*SS + iw];
          in[ic*16+kh*4+kw] = v;
        }
    #pragma unroll
    for (int g=0; g<4; g++) {
      __hip_bfloat16 outv[16];
      #pragma unroll
      for (int ocl=0; ocl<16; ocl++) {
        int oc = g*16 + ocl;
        float a = bias[oc];
        const float* wp = w + oc*48;             // wave-uniform -> scalar loads
        #pragma unroll
        for (int t=0; t<48; t++) a = fmaf(in[t], wp[t], a);
        a = a >= 0.f ? a : 0.2f*a;
        outv[ocl] = __float2bfloat16(a);
      }
      __hip_bfloat16* dst = h1 + (((size_t)g*BB + bi)*4096 + oh*64 + ow)*16;
      *(bf16x8*)(dst)     = *(bf16x8*)&outv[0];
      *(bf16x8*)(dst + 8) = *(bf16x8*)&outv[8];
    }
}

// ---------------- weight prep: w2 fp32 -> Bw bf16 [stage4][kl8 32][oc 128][jj 8] ----------------
__global__ __launch_bounds__(256) void k_prepw(const float* __restrict__ w2,
    __hip_bfloat16* __restrict__ Bw)
{
    int i = blockIdx.x*256 + threadIdx.x;        // 131072
    int jj = i & 7, oc = (i>>3)&127, kl8 = (i>>10)&31, stage = i>>15;
    int kl = kl8*8 + jj;                         // k-local within stage: tap*16 + icl
    int tap = kl >> 4, icl = kl & 15;
    int ic = stage*16 + icl;
    Bw[i] = __float2bfloat16(w2[(size_t)oc*1024 + ic*16 + tap]);
}

// ---------------- conv2 via MFMA bf16 implicit GEMM ----------------
__global__ __launch_bounds__(256) void k_conv2(const __hip_bfloat16* __restrict__ h1,
    const __hip_bfloat16* __restrict__ Bw, const float* __restrict__ b2,
    float* __restrict__ h2)
{
    int bx = blockIdx.x;
    int nh = bx & 1, strip = (bx>>1)&3, bi = bx>>3;
    int lane = threadIdx.x & 63, wv = threadIdx.x >> 6;
    int l15 = lane & 15, kg = lane >> 4;

    __shared__ __align__(16) short tile[36*33*24];   // 1188 rows x 48B = 57 KB

    f32x4 acc[4][4];
    #pragma unroll
    for (int m=0;m<4;m++)
      #pragma unroll
      for (int n=0;n<4;n++) acc[m][n] = (f32x4)(0.f);

    int ihb = strip*16 - 1;                      // global ih of ih_l=0

    for (int stage=0; stage<4; ++stage) {
      const __hip_bfloat16* hsrc = h1 + ((size_t)stage*BB + bi)*4096*16;
      for (int idx = threadIdx.x; idx < 2376; idx += 256) {
        int half = idx & 1, p = idx >> 1;        // p = ih_l*66 + iw_l
        int ih_l = p / 66, iw_l = p - ih_l*66;
        int ih = ihb + ih_l, iw = iw_l - 1;
        int row48 = (ih_l*2 + (iw_l&1))*33 + (iw_l>>1);
        bf16x8 v = (bf16x8)(0);
        if ((unsigned)ih < 64u && (unsigned)iw < 64u)
          v = *(const bf16x8*)(hsrc + ((size_t)(ih*64+iw)*16 + half*8));
        *(bf16x8*)&tile[row48*24 + half*8] = v;
      }
      __syncthreads();
      const __hip_bfloat16* bwst = Bw + (size_t)stage*32*128*8;
      #pragma unroll
      for (int j=0; j<8; j++) {
        bf16x8 bf[4];
        #pragma unroll
        for (int nf=0; nf<4; nf++)
          bf[nf] = *(const bf16x8*)(bwst + ((size_t)((j*4+kg)*128) + nh*64 + nf*16 + l15)*8);
        int tap = 2*j + (kg>>1);
        int kh = tap>>2, kw = tap&3;
        int icl0 = (kg&1)*8;
        bf16x8 af[4];
        #pragma unroll
        for (int mf=0; mf<4; mf++) {
          int oh_l = 2*wv + (mf>>1);
          int ow   = (mf&1)*16 + l15;
          int ih_l = 2*oh_l + kh;
          int iw_l = 2*ow + kw;
          int row48 = (ih_l*2 + (iw_l&1))*33 + (iw_l>>1);
          af[mf] = *(const bf16x8*)&tile[row48*24 + icl0];
        }
        #pragma unroll
        for (int mf=0; mf<4; mf++)
          #pragma unroll
          for (int nf=0; nf<4; nf++)
            acc[mf][nf] = __builtin_amdgcn_mfma_f32_16x16x32_bf16(af[mf], bf[nf], acc[mf][nf], 0, 0, 0);
      }
      __syncthreads();
    }
    #pragma unroll
    for (int mf=0; mf<4; mf++)
      #pragma unroll
      for (int nf=0; nf<4; nf++) {
        int oc = nh*64 + nf*16 + l15;
        int p0 = wv*64 + mf*16 + kg*4;
        float bv = b2[oc];
        float4 o;
        o.x = acc[mf][nf][0] + bv;
        o.y = acc[mf][nf][1] + bv;
        o.z = acc[mf][nf][2] + bv;
        o.w = acc[mf][nf][3] + bv;
        *(float4*)&h2[((size_t)bi*C2 + oc)*1024 + strip*256 + p0] = o;
      }
}

// ---------------- batchnorm stats (per channel), fp64 accumulate ----------------
__global__ __launch_bounds__(256) void k_bnstats(const float* __restrict__ h2,
    const float* __restrict__ gamma, const float* __restrict__ beta,
    float* __restrict__ stats)
{
    int c = blockIdx.x;     // 0..127
    double s1 = 0.0, s2 = 0.0;
    for (int i = threadIdx.x; i < BB*1024; i += 256) {
      int b = i >> 10, hw = i & 1023;
      double v = (double)h2[((size_t)b*C2 + c)*1024 + hw];
      s1 += v; s2 = fma(v, v, s2);
    }
    __shared__ double r1[256], r2[256];
    r1[threadIdx.x] = s1; r2[threadIdx.x] = s2;
    __syncthreads();
    for (int s = 128; s > 0; s >>= 1) {
      if (threadIdx.x < s) { r1[threadIdx.x] += r1[threadIdx.x+s]; r2[threadIdx.x] += r2[threadIdx.x+s]; }
      __syncthreads();
    }
    if (threadIdx.x == 0) {
      double mean = r1[0] * (1.0/65536.0);
      double var  = r2[0] * (1.0/65536.0) - mean*mean;
      double rstd = 1.0 / sqrt(var + 1e-5);
      double sc = rstd * (double)gamma[c];
      stats[c]      = (float)sc;                           // scale
      stats[C2 + c] = (float)((double)beta[c] - mean*sc);  // shift
    }
}

// ---------------- BN apply + leaky: IN-PLACE h2 (fp32 feat) + featb (bf16 copy) ----------------
__global__ __launch_bounds__(256) void k_bnapply(float* __restrict__ h2,
    const float* __restrict__ stats, __hip_bfloat16* __restrict__ featb)
{
    int i = blockIdx.x*256 + threadIdx.x;       // float4 index
    int c = (i >> 8) & 127;
    float sc = stats[c], sh = stats[C2 + c];
    float4 v = ((const float4*)h2)[i];
    float4 o;
    o.x = fmaf(v.x, sc, sh); o.x = o.x >= 0.f ? o.x : 0.2f*o.x;
    o.y = fmaf(v.y, sc, sh); o.y = o.y >= 0.f ? o.y : 0.2f*o.y;
    o.z = fmaf(v.z, sc, sh); o.z = o.z >= 0.f ? o.z : 0.2f*o.z;
    o.w = fmaf(v.w, sc, sh); o.w = o.w >= 0.f ? o.w : 0.2f*o.w;
    ((float4*)h2)[i] = o;
    __hip_bfloat16 b[4];
    b[0] = __float2bfloat16(o.x); b[1] = __float2bfloat16(o.y);
    b[2] = __float2bfloat16(o.z); b[3] = __float2bfloat16(o.w);
    *(double*)(featb + (size_t)i*4) = *(double*)b;   // 8B store
}

// ---------------- M = featb @ T via MFMA (deterministic split-K) ----------------
// grid (4, KCH): ng = 128-col group, kc = K-chunk of 512.  4 waves: wave -> 32 cols.
// A = featb bf16 [64][131072]; B = T fp32 -> cvt bf16 in flight.
__global__ __launch_bounds__(256) void k_mgemm(const __hip_bfloat16* __restrict__ featb,
    const float* __restrict__ T, float* __restrict__ Mpart)
{
    int lane = threadIdx.x & 63, wv = threadIdx.x >> 6;
    int l15 = lane & 15, kg = lane >> 4;
    int ng = blockIdx.x;                   // 0..3
    int kc = blockIdx.y;                   // 0..KCH-1
    int k0b = kc * KCSZ;
    int colbase = ng*128 + wv*32;

    f32x4 acc[4][2];
    #pragma unroll
    for (int m=0;m<4;m++) { acc[m][0] = (f32x4)(0.f); acc[m][1] = (f32x4)(0.f); }

    for (int ks = 0; ks < KCSZ/32; ks++) {
      int k0 = k0b + ks*32;
      bf16x8 af[4];
      #pragma unroll
      for (int mf=0; mf<4; mf++)
        af[mf] = *(const bf16x8*)(featb + (size_t)(mf*16 + l15)*FLAT + k0 + kg*8);
      bf16x8 bfr[2];
      #pragma unroll
      for (int nf=0; nf<2; nf++) {
        int col = colbase + nf*16 + l15;
        __hip_bfloat16 tb[8];
        #pragma unroll
        for (int j=0;j<8;j++) {
          int k = k0 + kg*8 + j;
          float tv = (col < NCOL) ? T[(size_t)k*NCOL + col] : 0.f;
          tb[j] = __float2bfloat16(tv);
        }
        bfr[nf] = *(bf16x8*)tb;
      }
      #pragma unroll
      for (int mf=0;mf<4;mf++)
        #pragma unroll
        for (int nf=0;nf<2;nf++)
          acc[mf][nf] = __builtin_amdgcn_mfma_f32_16x16x32_bf16(af[mf], bfr[nf], acc[mf][nf], 0, 0, 0);
    }
    // D layout: row = mf*16 + kg*4 + q, col = colbase + nf*16 + l15
    float* op = Mpart + (size_t)kc*64*512;
    #pragma unroll
    for (int mf=0;mf<4;mf++)
      #pragma unroll
      for (int nf=0;nf<2;nf++) {
        int col = colbase + nf*16 + l15;
        int r0 = mf*16 + kg*4;
        op[(size_t)(r0+0)*512 + col] = acc[mf][nf][0];
        op[(size_t)(r0+1)*512 + col] = acc[mf][nf][1];
        op[(size_t)(r0+2)*512 + col] = acc[mf][nf][2];
        op[(size_t)(r0+3)*512 + col] = acc[mf][nf][3];
      }
}

__global__ __launch_bounds__(256) void k_mreduce(const float* __restrict__ Mpart,
    float* __restrict__ M)
{
    int i = blockIdx.x*256 + threadIdx.x;   // 32000 = 64*500
    int r = i / NCOL, c = i - r*NCOL;
    float s = 0.f;
    const float* p = Mpart + (size_t)r*512 + c;
    #pragma unroll 8
    for (int kc = 0; kc < KCH; kc++) s += p[(size_t)kc*64*512];
    M[i] = s;
}

// ---------------- minibatch discrimination: o_b ----------------
__global__ __launch_bounds__(256) void k_ob(const float* __restrict__ M,
    float* __restrict__ ob)
{
    int o = blockIdx.x;   // 0..99
    __shared__ float Ms[320];
    __shared__ float red[256];
    for (int idx = threadIdx.x; idx < 320; idx += 256) {
      int a = idx / 5, d = idx - a*5;
      Ms[idx] = M[(size_t)a*NCOL + o*5 + d];
    }
    __syncthreads();
    int b = threadIdx.x & 63, aq = threadIdx.x >> 6;
    float s = 0.f;
    for (int a = aq*16; a < aq*16+16; a++) {
      float n = 0.f;
      #pragma unroll
      for (int d=0; d<5; d++) n += fabsf(Ms[a*5+d] - Ms[b*5+d]);
      s += expf(-n);
    }
    red[threadIdx.x] = s;
    __syncthreads();
    if (threadIdx.x < 64)
      ob[(size_t)b*100 + o] = red[b] + red[64+b] + red[128+b] + red[192+b];
}

// ---------------- final linear + sigmoid (fp64 accumulate) ----------------
__global__ __launch_bounds__(256) void k_final(const float* __restrict__ feat,
    const float* __restrict__ ob, const float* __restrict__ lw,
    const float* __restrict__ lb, float* __restrict__ out)
{
    int b = blockIdx.x;
    const float4* fp = (const float4*)(feat + (size_t)b*FLAT);
    const float4* wp = (const float4*)lw;
    double s = 0.0;
    for (int j = threadIdx.x; j < FLAT/4; j += 256) {
      float4 f = fp[j], w = wp[j];
      s = fma((double)f.x, (double)w.x, s);
      s = fma((double)f.y, (double)w.y, s);
      s = fma((double)f.z, (double)w.z, s);
      s = fma((double)f.w, (double)w.w, s);
    }
    if (threadIdx.x < 100)
      s = fma((double)ob[(size_t)b*100 + threadIdx.x], (double)lw[FLAT + threadIdx.x], s);
    __shared__ double red[256];
    red[threadIdx.x] = s;
    __syncthreads();
    for (int st = 128; st > 0; st >>= 1) {
      if (threadIdx.x < st) red[threadIdx.x] += red[threadIdx.x + st];
      __syncthreads();
    }
    if (threadIdx.x == 0) {
      double logit = red[0] + (double)lb[0];
      out[b] = (float)(1.0 / (1.0 + exp(-logit)));
    }
}

extern "C" void kernel_launch(void* const* d_in, const int* in_sizes, int n_in,
                              void* d_out, int out_size, void* d_ws, size_t ws_size,
                              hipStream_t stream)
{
    const float* x   = (const float*)d_in[0];
    const float* w1  = (const float*)d_in[1];
    const float* b1  = (const float*)d_in[2];
    const float* w2  = (const float*)d_in[3];
    const float* b2  = (const float*)d_in[4];
    const float* gam = (const float*)d_in[5];
    const float* bet = (const float*)d_in[6];
    const float* T   = (const float*)d_in[7];
    const float* lw  = (const float*)d_in[8];
    const float* lb  = (const float*)d_in[9];
    float* out = (float*)d_out;

    float* ws = (float*)d_ws;
    // Layout (floats):
    //   [0 .. 8,388,608)            h1 bf16 (33.5MB) -> later Mpart fp32 [256][64][512] (33.5MB exact)
    //   [8,388,608 .. 16,777,216)   h2 fp32 (in-place BN -> feat)
    //   [16,777,216 ..)             Bw bf16 (65536 fl) | M (32000) | stats (256) | ob (6400)
    //   [16,841,408+others ..)      featb bf16 (4,194,304 floats worth = 16.8MB)
    // Total ~84.3 MB (proven ws >= ~100.8 MB).
    __hip_bfloat16* h1 = (__hip_bfloat16*)ws;
    float* Mpart = ws;                               // aliases h1 (dead after conv2)
    float* h2    = ws + 8388608;
    float* feat  = h2;                               // in-place BN
    __hip_bfloat16* Bw = (__hip_bfloat16*)(ws + 16777216);
    float* M     = ws + 16777216 + 65536;
    float* stats = M + 32000;
    float* ob    = stats + 256;
    __hip_bfloat16* featb = (__hip_bfloat16*)(ob + 6400);

    k_prepw<<<512, 256, 0, stream>>>(w2, Bw);
    k_conv1<<<1024, 256, 0, stream>>>(x, w1, b1, h1);
    k_conv2<<<512, 256, 0, stream>>>(h1, Bw, b2, h2);
    k_bnstats<<<128, 256, 0, stream>>>(h2, gam, bet, stats);
    k_bnapply<<<8192, 256, 0, stream>>>(h2, stats, featb);
    k_mgemm<<<dim3(4, KCH), 256, 0, stream>>>(featb, T, Mpart);
    k_mreduce<<<125, 256, 0, stream>>>(Mpart, M);
    k_ob<<<100, 256, 0, stream>>>(M, ob);
    k_final<<<64, 256, 0, stream>>>(feat, ob, lw, lb, out);
}

// Round 7
// 323.729 us; speedup vs baseline: 6.9269x; 1.2216x over previous
//
#include <hip/hip_runtime.h>
#include <hip/hip_bf16.h>
#include <math.h>

#define BB 64
#define SS 128
#define C1 64
#define H1D 64
#define C2 128
#define H2D 32
#define FLAT 131072
#define NCOL 500
#define KCH 512      // split-K chunks in mgemm (deterministic partials, bf16)
#define KCSZ 256     // k per chunk  (KCH*KCSZ == FLAT)

typedef __attribute__((ext_vector_type(4))) float f32x4;
typedef __attribute__((ext_vector_type(8))) short bf16x8;

// ---------------- conv1 (4x4 s2 p1) + leaky -> h1 bf16 [g4][b][oh][ow][16ic] ----------------
__global__ __launch_bounds__(256) void k_conv1(const float* __restrict__ x,
    const float* __restrict__ w, const float* __restrict__ bias,
    __hip_bfloat16* __restrict__ h1)
{
    int tid = blockIdx.x*256 + threadIdx.x;      // (b, oh, ow)
    int ow = tid & 63, oh = (tid>>6)&63, bi = tid>>12;
    int ih0 = oh*2-1, iw0 = ow*2-1;
    float in[48];
    #pragma unroll
    for (int ic=0; ic<3; ic++)
      #pragma unroll
      for (int kh=0; kh<4; kh++)
        #pragma unroll
        for (int kw=0; kw<4; kw++) {
          int ih = ih0+kh, iw = iw0+kw;
          float v = 0.f;
          if ((unsigned)ih < 128u && (unsigned)iw < 128u)
            v = x[((size_t)(bi*3+ic)*SS + ih)*SS + iw];
          in[ic*16+kh*4+kw] = v;
        }
    #pragma unroll
    for (int g=0; g<4; g++) {
      __hip_bfloat16 outv[16];
      #pragma unroll
      for (int ocl=0; ocl<16; ocl++) {
        int oc = g*16 + ocl;
        float a = bias[oc];
        const float* wp = w + oc*48;             // wave-uniform -> scalar loads
        #pragma unroll
        for (int t=0; t<48; t++) a = fmaf(in[t], wp[t], a);
        a = a >= 0.f ? a : 0.2f*a;
        outv[ocl] = __float2bfloat16(a);
      }
      __hip_bfloat16* dst = h1 + (((size_t)g*BB + bi)*4096 + oh*64 + ow)*16;
      *(bf16x8*)(dst)     = *(bf16x8*)&outv[0];
      *(bf16x8*)(dst + 8) = *(bf16x8*)&outv[8];
    }
}

// ---------------- weight prep: w2 fp32 -> Bw bf16 [stage4][kl8 32][oc 128][jj 8] ----------------
__global__ __launch_bounds__(256) void k_prepw(const float* __restrict__ w2,
    __hip_bfloat16* __restrict__ Bw)
{
    int i = blockIdx.x*256 + threadIdx.x;        // 131072
    int jj = i & 7, oc = (i>>3)&127, kl8 = (i>>10)&31, stage = i>>15;
    int kl = kl8*8 + jj;                         // k-local within stage: tap*16 + icl
    int tap = kl >> 4, icl = kl & 15;
    int ic = stage*16 + icl;
    Bw[i] = __float2bfloat16(w2[(size_t)oc*1024 + ic*16 + tap]);
}

// ---------------- conv2 via MFMA bf16 implicit GEMM ----------------
__global__ __launch_bounds__(256) void k_conv2(const __hip_bfloat16* __restrict__ h1,
    const __hip_bfloat16* __restrict__ Bw, const float* __restrict__ b2,
    float* __restrict__ h2)
{
    int bx = blockIdx.x;
    int nh = bx & 1, strip = (bx>>1)&3, bi = bx>>3;
    int lane = threadIdx.x & 63, wv = threadIdx.x >> 6;
    int l15 = lane & 15, kg = lane >> 4;

    __shared__ __align__(16) short tile[36*33*24];   // 1188 rows x 48B = 57 KB

    f32x4 acc[4][4];
    #pragma unroll
    for (int m=0;m<4;m++)
      #pragma unroll
      for (int n=0;n<4;n++) acc[m][n] = (f32x4)(0.f);

    int ihb = strip*16 - 1;                      // global ih of ih_l=0

    for (int stage=0; stage<4; ++stage) {
      const __hip_bfloat16* hsrc = h1 + ((size_t)stage*BB + bi)*4096*16;
      for (int idx = threadIdx.x; idx < 2376; idx += 256) {
        int half = idx & 1, p = idx >> 1;        // p = ih_l*66 + iw_l
        int ih_l = p / 66, iw_l = p - ih_l*66;
        int ih = ihb + ih_l, iw = iw_l - 1;
        int row48 = (ih_l*2 + (iw_l&1))*33 + (iw_l>>1);
        bf16x8 v = (bf16x8)(0);
        if ((unsigned)ih < 64u && (unsigned)iw < 64u)
          v = *(const bf16x8*)(hsrc + ((size_t)(ih*64+iw)*16 + half*8));
        *(bf16x8*)&tile[row48*24 + half*8] = v;
      }
      __syncthreads();
      const __hip_bfloat16* bwst = Bw + (size_t)stage*32*128*8;
      #pragma unroll
      for (int j=0; j<8; j++) {
        bf16x8 bf[4];
        #pragma unroll
        for (int nf=0; nf<4; nf++)
          bf[nf] = *(const bf16x8*)(bwst + ((size_t)((j*4+kg)*128) + nh*64 + nf*16 + l15)*8);
        int tap = 2*j + (kg>>1);
        int kh = tap>>2, kw = tap&3;
        int icl0 = (kg&1)*8;
        bf16x8 af[4];
        #pragma unroll
        for (int mf=0; mf<4; mf++) {
          int oh_l = 2*wv + (mf>>1);
          int ow   = (mf&1)*16 + l15;
          int ih_l = 2*oh_l + kh;
          int iw_l = 2*ow + kw;
          int row48 = (ih_l*2 + (iw_l&1))*33 + (iw_l>>1);
          af[mf] = *(const bf16x8*)&tile[row48*24 + icl0];
        }
        #pragma unroll
        for (int mf=0; mf<4; mf++)
          #pragma unroll
          for (int nf=0; nf<4; nf++)
            acc[mf][nf] = __builtin_amdgcn_mfma_f32_16x16x32_bf16(af[mf], bf[nf], acc[mf][nf], 0, 0, 0);
      }
      __syncthreads();
    }
    #pragma unroll
    for (int mf=0; mf<4; mf++)
      #pragma unroll
      for (int nf=0; nf<4; nf++) {
        int oc = nh*64 + nf*16 + l15;
        int p0 = wv*64 + mf*16 + kg*4;
        float bv = b2[oc];
        float4 o;
        o.x = acc[mf][nf][0] + bv;
        o.y = acc[mf][nf][1] + bv;
        o.z = acc[mf][nf][2] + bv;
        o.w = acc[mf][nf][3] + bv;
        *(float4*)&h2[((size_t)bi*C2 + oc)*1024 + strip*256 + p0] = o;
      }
}

// ---------------- batchnorm stats, 2-stage fp64 ----------------
// stage1: 1024 blocks = (c 0..127) x (s 0..7); each sums 8 batch images of channel c
__global__ __launch_bounds__(256) void k_bnstats1(const float* __restrict__ h2,
    double* __restrict__ bnp)
{
    int c = blockIdx.x & 127, s = blockIdx.x >> 7;
    double s1 = 0.0, s2 = 0.0;
    for (int i = threadIdx.x; i < 8*1024; i += 256) {
      int b = s*8 + (i >> 10), hw = i & 1023;
      double v = (double)h2[((size_t)b*C2 + c)*1024 + hw];
      s1 += v; s2 = fma(v, v, s2);
    }
    __shared__ double r1[256], r2[256];
    r1[threadIdx.x] = s1; r2[threadIdx.x] = s2;
    __syncthreads();
    for (int st = 128; st > 0; st >>= 1) {
      if (threadIdx.x < st) { r1[threadIdx.x] += r1[threadIdx.x+st]; r2[threadIdx.x] += r2[threadIdx.x+st]; }
      __syncthreads();
    }
    if (threadIdx.x == 0) {
      bnp[c*8 + s]        = r1[0];
      bnp[1024 + c*8 + s] = r2[0];
    }
}

__global__ void k_bnstats2(const double* __restrict__ bnp,
    const float* __restrict__ gamma, const float* __restrict__ beta,
    float* __restrict__ stats)
{
    int c = threadIdx.x;   // 128 threads, 1 block
    double s1 = 0.0, s2 = 0.0;
    #pragma unroll
    for (int s = 0; s < 8; s++) { s1 += bnp[c*8+s]; s2 += bnp[1024 + c*8+s]; }
    double mean = s1 * (1.0/65536.0);
    double var  = s2 * (1.0/65536.0) - mean*mean;
    double rstd = 1.0 / sqrt(var + 1e-5);
    double sc = rstd * (double)gamma[c];
    stats[c]      = (float)sc;
    stats[C2 + c] = (float)((double)beta[c] - mean*sc);
}

// ---------------- BN apply + leaky -> featb (bf16 only; h2 stays raw) ----------------
__global__ __launch_bounds__(256) void k_bnapply(const float* __restrict__ h2,
    const float* __restrict__ stats, __hip_bfloat16* __restrict__ featb)
{
    int i = blockIdx.x*256 + threadIdx.x;       // float4 index
    int c = (i >> 8) & 127;
    float sc = stats[c], sh = stats[C2 + c];
    float4 v = ((const float4*)h2)[i];
    float4 o;
    o.x = fmaf(v.x, sc, sh); o.x = o.x >= 0.f ? o.x : 0.2f*o.x;
    o.y = fmaf(v.y, sc, sh); o.y = o.y >= 0.f ? o.y : 0.2f*o.y;
    o.z = fmaf(v.z, sc, sh); o.z = o.z >= 0.f ? o.z : 0.2f*o.z;
    o.w = fmaf(v.w, sc, sh); o.w = o.w >= 0.f ? o.w : 0.2f*o.w;
    __hip_bfloat16 b[4];
    b[0] = __float2bfloat16(o.x); b[1] = __float2bfloat16(o.y);
    b[2] = __float2bfloat16(o.z); b[3] = __float2bfloat16(o.w);
    *(double*)(featb + (size_t)i*4) = *(double*)b;   // 8B store
}

// ---------------- M = featb @ T via MFMA (deterministic split-K, bf16 partials) ----------------
// grid (4, KCH=512): ng = 128-col group, kc = K-chunk of 256.  8 blocks/CU -> 32 waves/CU.
__global__ __launch_bounds__(256, 8) void k_mgemm(const __hip_bfloat16* __restrict__ featb,
    const float* __restrict__ T, __hip_bfloat16* __restrict__ Mpart)
{
    int lane = threadIdx.x & 63, wv = threadIdx.x >> 6;
    int l15 = lane & 15, kg = lane >> 4;
    int ng = blockIdx.x;                   // 0..3
    int kc = blockIdx.y;                   // 0..KCH-1
    int k0b = kc * KCSZ;
    int colbase = ng*128 + wv*32;

    f32x4 acc[4][2];
    #pragma unroll
    for (int m=0;m<4;m++) { acc[m][0] = (f32x4)(0.f); acc[m][1] = (f32x4)(0.f); }

    for (int ks = 0; ks < KCSZ/32; ks++) {
      int k0 = k0b + ks*32;
      bf16x8 af[4];
      #pragma unroll
      for (int mf=0; mf<4; mf++)
        af[mf] = *(const bf16x8*)(featb + (size_t)(mf*16 + l15)*FLAT + k0 + kg*8);
      bf16x8 bfr[2];
      #pragma unroll
      for (int nf=0; nf<2; nf++) {
        int col = colbase + nf*16 + l15;
        __hip_bfloat16 tb[8];
        #pragma unroll
        for (int j=0;j<8;j++) {
          int k = k0 + kg*8 + j;
          float tv = (col < NCOL) ? T[(size_t)k*NCOL + col] : 0.f;
          tb[j] = __float2bfloat16(tv);
        }
        bfr[nf] = *(bf16x8*)tb;
      }
      #pragma unroll
      for (int mf=0;mf<4;mf++)
        #pragma unroll
        for (int nf=0;nf<2;nf++)
          acc[mf][nf] = __builtin_amdgcn_mfma_f32_16x16x32_bf16(af[mf], bfr[nf], acc[mf][nf], 0, 0, 0);
    }
    // D layout: row = mf*16 + kg*4 + q, col = colbase + nf*16 + l15
    __hip_bfloat16* op = Mpart + (size_t)kc*64*512;
    #pragma unroll
    for (int mf=0;mf<4;mf++)
      #pragma unroll
      for (int nf=0;nf<2;nf++) {
        int col = colbase + nf*16 + l15;
        int r0 = mf*16 + kg*4;
        op[(size_t)(r0+0)*512 + col] = __float2bfloat16(acc[mf][nf][0]);
        op[(size_t)(r0+1)*512 + col] = __float2bfloat16(acc[mf][nf][1]);
        op[(size_t)(r0+2)*512 + col] = __float2bfloat16(acc[mf][nf][2]);
        op[(size_t)(r0+3)*512 + col] = __float2bfloat16(acc[mf][nf][3]);
      }
}

__global__ __launch_bounds__(256) void k_mreduce(const __hip_bfloat16* __restrict__ Mpart,
    float* __restrict__ M)
{
    int i = blockIdx.x*256 + threadIdx.x;   // 32000 = 64*500
    int r = i / NCOL, c = i - r*NCOL;
    float s = 0.f;
    const __hip_bfloat16* p = Mpart + (size_t)r*512 + c;
    #pragma unroll 8
    for (int kc = 0; kc < KCH; kc++) s += __bfloat162float(p[(size_t)kc*64*512]);
    M[i] = s;
}

// ---------------- minibatch discrimination: o_b ----------------
__global__ __launch_bounds__(256) void k_ob(const float* __restrict__ M,
    float* __restrict__ ob)
{
    int o = blockIdx.x;   // 0..99
    __shared__ float Ms[320];
    __shared__ float red[256];
    for (int idx = threadIdx.x; idx < 320; idx += 256) {
      int a = idx / 5, d = idx - a*5;
      Ms[idx] = M[(size_t)a*NCOL + o*5 + d];
    }
    __syncthreads();
    int b = threadIdx.x & 63, aq = threadIdx.x >> 6;
    float s = 0.f;
    for (int a = aq*16; a < aq*16+16; a++) {
      float n = 0.f;
      #pragma unroll
      for (int d=0; d<5; d++) n += fabsf(Ms[a*5+d] - Ms[b*5+d]);
      s += expf(-n);
    }
    red[threadIdx.x] = s;
    __syncthreads();
    if (threadIdx.x < 64)
      ob[(size_t)b*100 + o] = red[b] + red[64+b] + red[128+b] + red[192+b];
}

// ---------------- final linear: stage1 partial dots (BN applied inline from raw h2) ----------------
__global__ __launch_bounds__(256) void k_final1(const float* __restrict__ h2,
    const float* __restrict__ stats, const float* __restrict__ lw,
    double* __restrict__ fpart)
{
    int bx = blockIdx.x;          // 512 = b*8 + s
    int b = bx >> 3, s = bx & 7;
    const float4* fp = (const float4*)(h2 + (size_t)b*FLAT);
    const float4* wp = (const float4*)lw;
    double acc = 0.0;
    for (int j = s*4096 + threadIdx.x; j < (s+1)*4096; j += 256) {
      int c = (j >> 8) & 127;
      float sc = stats[c], sh = stats[C2 + c];
      float4 v = fp[j], w = wp[j];
      float4 o;
      o.x = fmaf(v.x, sc, sh); o.x = o.x >= 0.f ? o.x : 0.2f*o.x;
      o.y = fmaf(v.y, sc, sh); o.y = o.y >= 0.f ? o.y : 0.2f*o.y;
      o.z = fmaf(v.z, sc, sh); o.z = o.z >= 0.f ? o.z : 0.2f*o.z;
      o.w = fmaf(v.w, sc, sh); o.w = o.w >= 0.f ? o.w : 0.2f*o.w;
      acc = fma((double)o.x, (double)w.x, acc);
      acc = fma((double)o.y, (double)w.y, acc);
      acc = fma((double)o.z, (double)w.z, acc);
      acc = fma((double)o.w, (double)w.w, acc);
    }
    __shared__ double red[256];
    red[threadIdx.x] = acc;
    __syncthreads();
    for (int st = 128; st > 0; st >>= 1) {
      if (threadIdx.x < st) red[threadIdx.x] += red[threadIdx.x + st];
      __syncthreads();
    }
    if (threadIdx.x == 0) fpart[bx] = red[0];
}

__global__ void k_final2(const double* __restrict__ fpart,
    const float* __restrict__ ob, const float* __restrict__ lw,
    const float* __restrict__ lb, float* __restrict__ out)
{
    int b = threadIdx.x;   // 64 threads, 1 block
    double s = 0.0;
    #pragma unroll
    for (int i = 0; i < 8; i++) s += fpart[b*8 + i];
    for (int o = 0; o < 100; o++)
      s = fma((double)ob[(size_t)b*100 + o], (double)lw[FLAT + o], s);
    s += (double)lb[0];
    out[b] = (float)(1.0 / (1.0 + exp(-s)));
}

extern "C" void kernel_launch(void* const* d_in, const int* in_sizes, int n_in,
                              void* d_out, int out_size, void* d_ws, size_t ws_size,
                              hipStream_t stream)
{
    const float* x   = (const float*)d_in[0];
    const float* w1  = (const float*)d_in[1];
    const float* b1  = (const float*)d_in[2];
    const float* w2  = (const float*)d_in[3];
    const float* b2  = (const float*)d_in[4];
    const float* gam = (const float*)d_in[5];
    const float* bet = (const float*)d_in[6];
    const float* T   = (const float*)d_in[7];
    const float* lw  = (const float*)d_in[8];
    const float* lb  = (const float*)d_in[9];
    float* out = (float*)d_out;

    float* ws = (float*)d_ws;
    // Layout (float offsets):
    //   [0 .. 8,388,608)            h1 bf16 [4][64][4096][16]  -> later Mpart bf16 [512][64][512] (exact alias)
    //   [8,388,608 .. 16,777,216)   h2 fp32 (stays RAW; BN applied inline downstream)
    //   [16,777,216 .. +65,536)     Bw bf16
    //   then M (32000 f32), stats (256 f32), ob (6400 f32)
    //   then featb bf16 (4,194,304 float-slots)
    //   then bnp (2048 doubles = 4096 floats), fpart (512 doubles = 1024 floats)
    // Total ~84.3 MB (proven ws >= ~100.8 MB).
    __hip_bfloat16* h1 = (__hip_bfloat16*)ws;
    __hip_bfloat16* Mpart = (__hip_bfloat16*)ws;     // aliases h1 (dead after conv2)
    float* h2    = ws + 8388608;
    __hip_bfloat16* Bw = (__hip_bfloat16*)(ws + 16777216);
    float* M     = ws + 16777216 + 65536;
    float* stats = M + 32000;
    float* ob    = stats + 256;
    __hip_bfloat16* featb = (__hip_bfloat16*)(ob + 6400);
    double* bnp   = (double*)(ob + 6400 + 4194304);
    double* fpart = bnp + 2048;

    k_prepw<<<512, 256, 0, stream>>>(w2, Bw);
    k_conv1<<<1024, 256, 0, stream>>>(x, w1, b1, h1);
    k_conv2<<<512, 256, 0, stream>>>(h1, Bw, b2, h2);
    k_bnstats1<<<1024, 256, 0, stream>>>(h2, bnp);
    k_bnstats2<<<1, 128, 0, stream>>>(bnp, gam, bet, stats);
    k_bnapply<<<8192, 256, 0, stream>>>(h2, stats, featb);
    k_mgemm<<<dim3(4, KCH), 256, 0, stream>>>(featb, T, Mpart);
    k_mreduce<<<125, 256, 0, stream>>>(Mpart, M);
    k_ob<<<100, 256, 0, stream>>>(M, ob);
    k_final1<<<512, 256, 0, stream>>>(h2, stats, lw, fpart);
    k_final2<<<1, 64, 0, stream>>>(fpart, ob, lw, lb, out);
}

// Round 8
// 319.719 us; speedup vs baseline: 7.0138x; 1.0125x over previous
//
#include <hip/hip_runtime.h>
#include <hip/hip_bf16.h>
#include <math.h>

#define BB 64
#define SS 128
#define C1 64
#define H1D 64
#define C2 128
#define H2D 32
#define FLAT 131072
#define NCOL 500
#define KCH 512      // split-K chunks in mgemm (deterministic partials, bf16)
#define KCSZ 256     // k per chunk  (KCH*KCSZ == FLAT)

typedef __attribute__((ext_vector_type(4))) float f32x4;
typedef __attribute__((ext_vector_type(8))) short bf16x8;

// ---------------- conv1 (4x4 s2 p1) + leaky -> h1 bf16 [g4][b][oh][ow][16ic] ----------------
__global__ __launch_bounds__(256) void k_conv1(const float* __restrict__ x,
    const float* __restrict__ w, const float* __restrict__ bias,
    __hip_bfloat16* __restrict__ h1)
{
    int tid = blockIdx.x*256 + threadIdx.x;      // (b, oh, ow)
    int ow = tid & 63, oh = (tid>>6)&63, bi = tid>>12;
    int ih0 = oh*2-1, iw0 = ow*2-1;
    float in[48];
    #pragma unroll
    for (int ic=0; ic<3; ic++)
      #pragma unroll
      for (int kh=0; kh<4; kh++)
        #pragma unroll
        for (int kw=0; kw<4; kw++) {
          int ih = ih0+kh, iw = iw0+kw;
          float v = 0.f;
          if ((unsigned)ih < 128u && (unsigned)iw < 128u)
            v = x[((size_t)(bi*3+ic)*SS + ih)*SS + iw];
          in[ic*16+kh*4+kw] = v;
        }
    #pragma unroll
    for (int g=0; g<4; g++) {
      __hip_bfloat16 outv[16];
      #pragma unroll
      for (int ocl=0; ocl<16; ocl++) {
        int oc = g*16 + ocl;
        float a = bias[oc];
        const float* wp = w + oc*48;             // wave-uniform -> scalar loads
        #pragma unroll
        for (int t=0; t<48; t++) a = fmaf(in[t], wp[t], a);
        a = a >= 0.f ? a : 0.2f*a;
        outv[ocl] = __float2bfloat16(a);
      }
      __hip_bfloat16* dst = h1 + (((size_t)g*BB + bi)*4096 + oh*64 + ow)*16;
      *(bf16x8*)(dst)     = *(bf16x8*)&outv[0];
      *(bf16x8*)(dst + 8) = *(bf16x8*)&outv[8];
    }
}

// ---------------- weight prep: w2 fp32 -> Bw bf16 [stage4][kl8 32][oc 128][jj 8] ----------------
__global__ __launch_bounds__(256) void k_prepw(const float* __restrict__ w2,
    __hip_bfloat16* __restrict__ Bw)
{
    int i = blockIdx.x*256 + threadIdx.x;        // 131072
    int jj = i & 7, oc = (i>>3)&127, kl8 = (i>>10)&31, stage = i>>15;
    int kl = kl8*8 + jj;                         // k-local within stage: tap*16 + icl
    int tap = kl >> 4, icl = kl & 15;
    int ic = stage*16 + icl;
    Bw[i] = __float2bfloat16(w2[(size_t)oc*1024 + ic*16 + tap]);
}

// ---------------- conv2 via MFMA bf16 implicit GEMM ----------------
__global__ __launch_bounds__(256) void k_conv2(const __hip_bfloat16* __restrict__ h1,
    const __hip_bfloat16* __restrict__ Bw, const float* __restrict__ b2,
    float* __restrict__ h2)
{
    int bx = blockIdx.x;
    int nh = bx & 1, strip = (bx>>1)&3, bi = bx>>3;
    int lane = threadIdx.x & 63, wv = threadIdx.x >> 6;
    int l15 = lane & 15, kg = lane >> 4;

    __shared__ __align__(16) short tile[36*33*24];   // 1188 rows x 48B = 57 KB

    f32x4 acc[4][4];
    #pragma unroll
    for (int m=0;m<4;m++)
      #pragma unroll
      for (int n=0;n<4;n++) acc[m][n] = (f32x4)(0.f);

    int ihb = strip*16 - 1;                      // global ih of ih_l=0

    for (int stage=0; stage<4; ++stage) {
      const __hip_bfloat16* hsrc = h1 + ((size_t)stage*BB + bi)*4096*16;
      for (int idx = threadIdx.x; idx < 2376; idx += 256) {
        int half = idx & 1, p = idx >> 1;        // p = ih_l*66 + iw_l
        int ih_l = p / 66, iw_l = p - ih_l*66;
        int ih = ihb + ih_l, iw = iw_l - 1;
        int row48 = (ih_l*2 + (iw_l&1))*33 + (iw_l>>1);
        bf16x8 v = (bf16x8)(0);
        if ((unsigned)ih < 64u && (unsigned)iw < 64u)
          v = *(const bf16x8*)(hsrc + ((size_t)(ih*64+iw)*16 + half*8));
        *(bf16x8*)&tile[row48*24 + half*8] = v;
      }
      __syncthreads();
      const __hip_bfloat16* bwst = Bw + (size_t)stage*32*128*8;
      #pragma unroll
      for (int j=0; j<8; j++) {
        bf16x8 bf[4];
        #pragma unroll
        for (int nf=0; nf<4; nf++)
          bf[nf] = *(const bf16x8*)(bwst + ((size_t)((j*4+kg)*128) + nh*64 + nf*16 + l15)*8);
        int tap = 2*j + (kg>>1);
        int kh = tap>>2, kw = tap&3;
        int icl0 = (kg&1)*8;
        bf16x8 af[4];
        #pragma unroll
        for (int mf=0; mf<4; mf++) {
          int oh_l = 2*wv + (mf>>1);
          int ow   = (mf&1)*16 + l15;
          int ih_l = 2*oh_l + kh;
          int iw_l = 2*ow + kw;
          int row48 = (ih_l*2 + (iw_l&1))*33 + (iw_l>>1);
          af[mf] = *(const bf16x8*)&tile[row48*24 + icl0];
        }
        #pragma unroll
        for (int mf=0; mf<4; mf++)
          #pragma unroll
          for (int nf=0; nf<4; nf++)
            acc[mf][nf] = __builtin_amdgcn_mfma_f32_16x16x32_bf16(af[mf], bf[nf], acc[mf][nf], 0, 0, 0);
      }
      __syncthreads();
    }
    #pragma unroll
    for (int mf=0; mf<4; mf++)
      #pragma unroll
      for (int nf=0; nf<4; nf++) {
        int oc = nh*64 + nf*16 + l15;
        int p0 = wv*64 + mf*16 + kg*4;
        float bv = b2[oc];
        float4 o;
        o.x = acc[mf][nf][0] + bv;
        o.y = acc[mf][nf][1] + bv;
        o.z = acc[mf][nf][2] + bv;
        o.w = acc[mf][nf][3] + bv;
        *(float4*)&h2[((size_t)bi*C2 + oc)*1024 + strip*256 + p0] = o;
      }
}

// ---------------- batchnorm stats, 2-stage fp64 ----------------
__global__ __launch_bounds__(256) void k_bnstats1(const float* __restrict__ h2,
    double* __restrict__ bnp)
{
    int c = blockIdx.x & 127, s = blockIdx.x >> 7;
    double s1 = 0.0, s2 = 0.0;
    for (int i = threadIdx.x; i < 8*1024; i += 256) {
      int b = s*8 + (i >> 10), hw = i & 1023;
      double v = (double)h2[((size_t)b*C2 + c)*1024 + hw];
      s1 += v; s2 = fma(v, v, s2);
    }
    __shared__ double r1[256], r2[256];
    r1[threadIdx.x] = s1; r2[threadIdx.x] = s2;
    __syncthreads();
    for (int st = 128; st > 0; st >>= 1) {
      if (threadIdx.x < st) { r1[threadIdx.x] += r1[threadIdx.x+st]; r2[threadIdx.x] += r2[threadIdx.x+st]; }
      __syncthreads();
    }
    if (threadIdx.x == 0) {
      bnp[c*8 + s]        = r1[0];
      bnp[1024 + c*8 + s] = r2[0];
    }
}

__global__ void k_bnstats2(const double* __restrict__ bnp,
    const float* __restrict__ gamma, const float* __restrict__ beta,
    float* __restrict__ stats)
{
    int c = threadIdx.x;   // 128 threads, 1 block
    double s1 = 0.0, s2 = 0.0;
    #pragma unroll
    for (int s = 0; s < 8; s++) { s1 += bnp[c*8+s]; s2 += bnp[1024 + c*8+s]; }
    double mean = s1 * (1.0/65536.0);
    double var  = s2 * (1.0/65536.0) - mean*mean;
    double rstd = 1.0 / sqrt(var + 1e-5);
    double sc = rstd * (double)gamma[c];
    stats[c]      = (float)sc;
    stats[C2 + c] = (float)((double)beta[c] - mean*sc);
}

// ---------------- BN apply + leaky -> featb (bf16 only; h2 stays raw) ----------------
__global__ __launch_bounds__(256) void k_bnapply(const float* __restrict__ h2,
    const float* __restrict__ stats, __hip_bfloat16* __restrict__ featb)
{
    int i = blockIdx.x*256 + threadIdx.x;       // float4 index
    int c = (i >> 8) & 127;
    float sc = stats[c], sh = stats[C2 + c];
    float4 v = ((const float4*)h2)[i];
    float4 o;
    o.x = fmaf(v.x, sc, sh); o.x = o.x >= 0.f ? o.x : 0.2f*o.x;
    o.y = fmaf(v.y, sc, sh); o.y = o.y >= 0.f ? o.y : 0.2f*o.y;
    o.z = fmaf(v.z, sc, sh); o.z = o.z >= 0.f ? o.z : 0.2f*o.z;
    o.w = fmaf(v.w, sc, sh); o.w = o.w >= 0.f ? o.w : 0.2f*o.w;
    __hip_bfloat16 b[4];
    b[0] = __float2bfloat16(o.x); b[1] = __float2bfloat16(o.y);
    b[2] = __float2bfloat16(o.z); b[3] = __float2bfloat16(o.w);
    *(double*)(featb + (size_t)i*4) = *(double*)b;   // 8B store
}

// ---------------- M = featb @ T via MFMA (deterministic split-K, bf16 partials) ----------------
// grid (4, KCH=512): ng = 128-col group, kc = K-chunk of 256.  8 blocks/CU -> 32 waves/CU.
// Partials stored in THREAD-ORDER layout [kc*4+ng][mf 4][t 256][8] so every
// wave store is 4KB contiguous (R6's row/col-order bf16 stores were 32B
// chunks -> 5.7x HBM write amplification).
__global__ __launch_bounds__(256, 8) void k_mgemm(const __hip_bfloat16* __restrict__ featb,
    const float* __restrict__ T, __hip_bfloat16* __restrict__ Mpart)
{
    int lane = threadIdx.x & 63, wv = threadIdx.x >> 6;
    int l15 = lane & 15, kg = lane >> 6 ? 0 : lane >> 4;  // (kg recomputed below safely)
    kg = (threadIdx.x & 63) >> 4;
    int ng = blockIdx.x;                   // 0..3
    int kc = blockIdx.y;                   // 0..KCH-1
    int k0b = kc * KCSZ;
    int colbase = ng*128 + wv*32;

    f32x4 acc[4][2];
    #pragma unroll
    for (int m=0;m<4;m++) { acc[m][0] = (f32x4)(0.f); acc[m][1] = (f32x4)(0.f); }

    for (int ks = 0; ks < KCSZ/32; ks++) {
      int k0 = k0b + ks*32;
      bf16x8 af[4];
      #pragma unroll
      for (int mf=0; mf<4; mf++)
        af[mf] = *(const bf16x8*)(featb + (size_t)(mf*16 + l15)*FLAT + k0 + kg*8);
      bf16x8 bfr[2];
      #pragma unroll
      for (int nf=0; nf<2; nf++) {
        int col = colbase + nf*16 + l15;
        __hip_bfloat16 tb[8];
        #pragma unroll
        for (int j=0;j<8;j++) {
          int k = k0 + kg*8 + j;
          float tv = (col < NCOL) ? T[(size_t)k*NCOL + col] : 0.f;
          tb[j] = __float2bfloat16(tv);
        }
        bfr[nf] = *(bf16x8*)tb;
      }
      #pragma unroll
      for (int mf=0;mf<4;mf++)
        #pragma unroll
        for (int nf=0;nf<2;nf++)
          acc[mf][nf] = __builtin_amdgcn_mfma_f32_16x16x32_bf16(af[mf], bfr[nf], acc[mf][nf], 0, 0, 0);
    }
    // thread-order coalesced store: Mpart[(kc*4+ng)][mf][t][nf*4+q]
    __hip_bfloat16* op = Mpart + (size_t)(kc*4 + ng)*8192;
    int t = threadIdx.x;
    #pragma unroll
    for (int mf=0; mf<4; mf++) {
      __hip_bfloat16 buf[8];
      #pragma unroll
      for (int nf=0; nf<2; nf++)
        #pragma unroll
        for (int q=0; q<4; q++)
          buf[nf*4+q] = __float2bfloat16(acc[mf][nf][q]);
      *(bf16x8*)(op + ((size_t)mf*256 + t)*8) = *(bf16x8*)buf;
    }
}

// inverts the thread-order layout: r=mf*16+kg*4+q, c=ng*128+wv*32+nf*16+l15
__global__ __launch_bounds__(256) void k_mreduce(const __hip_bfloat16* __restrict__ Mpart,
    float* __restrict__ M)
{
    int i = blockIdx.x*256 + threadIdx.x;   // 32000 = 64*500
    int r = i / NCOL, c = i - r*NCOL;
    int mf = r >> 4, kg = (r >> 2) & 3, q = r & 3;
    int ng = c >> 7, wv = (c >> 5) & 3, nf = (c >> 4) & 1, l15 = c & 15;
    int t = wv*64 + kg*16 + l15;
    const __hip_bfloat16* p = Mpart + ((size_t)ng*1024 + mf*256 + t)*8 + nf*4 + q;
    float s = 0.f;
    #pragma unroll 8
    for (int kc = 0; kc < KCH; kc++) s += __bfloat162float(p[(size_t)kc*32768]);
    M[i] = s;
}

// ---------------- minibatch discrimination: o_b ----------------
__global__ __launch_bounds__(256) void k_ob(const float* __restrict__ M,
    float* __restrict__ ob)
{
    int o = blockIdx.x;   // 0..99
    __shared__ float Ms[320];
    __shared__ float red[256];
    for (int idx = threadIdx.x; idx < 320; idx += 256) {
      int a = idx / 5, d = idx - a*5;
      Ms[idx] = M[(size_t)a*NCOL + o*5 + d];
    }
    __syncthreads();
    int b = threadIdx.x & 63, aq = threadIdx.x >> 6;
    float s = 0.f;
    for (int a = aq*16; a < aq*16+16; a++) {
      float n = 0.f;
      #pragma unroll
      for (int d=0; d<5; d++) n += fabsf(Ms[a*5+d] - Ms[b*5+d]);
      s += expf(-n);
    }
    red[threadIdx.x] = s;
    __syncthreads();
    if (threadIdx.x < 64)
      ob[(size_t)b*100 + o] = red[b] + red[64+b] + red[128+b] + red[192+b];
}

// ---------------- final linear: stage1 partial dots (BN applied inline from raw h2) ----------------
__global__ __launch_bounds__(256) void k_final1(const float* __restrict__ h2,
    const float* __restrict__ stats, const float* __restrict__ lw,
    double* __restrict__ fpart)
{
    int bx = blockIdx.x;          // 512 = b*8 + s
    int b = bx >> 3, s = bx & 7;
    const float4* fp = (const float4*)(h2 + (size_t)b*FLAT);
    const float4* wp = (const float4*)lw;
    double acc = 0.0;
    for (int j = s*4096 + threadIdx.x; j < (s+1)*4096; j += 256) {
      int c = (j >> 8) & 127;
      float sc = stats[c], sh = stats[C2 + c];
      float4 v = fp[j], w = wp[j];
      float4 o;
      o.x = fmaf(v.x, sc, sh); o.x = o.x >= 0.f ? o.x : 0.2f*o.x;
      o.y = fmaf(v.y, sc, sh); o.y = o.y >= 0.f ? o.y : 0.2f*o.y;
      o.z = fmaf(v.z, sc, sh); o.z = o.z >= 0.f ? o.z : 0.2f*o.z;
      o.w = fmaf(v.w, sc, sh); o.w = o.w >= 0.f ? o.w : 0.2f*o.w;
      acc = fma((double)o.x, (double)w.x, acc);
      acc = fma((double)o.y, (double)w.y, acc);
      acc = fma((double)o.z, (double)w.z, acc);
      acc = fma((double)o.w, (double)w.w, acc);
    }
    __shared__ double red[256];
    red[threadIdx.x] = acc;
    __syncthreads();
    for (int st = 128; st > 0; st >>= 1) {
      if (threadIdx.x < st) red[threadIdx.x] += red[threadIdx.x + st];
      __syncthreads();
    }
    if (threadIdx.x == 0) fpart[bx] = red[0];
}

__global__ void k_final2(const double* __restrict__ fpart,
    const float* __restrict__ ob, const float* __restrict__ lw,
    const float* __restrict__ lb, float* __restrict__ out)
{
    int b = threadIdx.x;   // 64 threads, 1 block
    double s = 0.0;
    #pragma unroll
    for (int i = 0; i < 8; i++) s += fpart[b*8 + i];
    for (int o = 0; o < 100; o++)
      s = fma((double)ob[(size_t)b*100 + o], (double)lw[FLAT + o], s);
    s += (double)lb[0];
    out[b] = (float)(1.0 / (1.0 + exp(-s)));
}

extern "C" void kernel_launch(void* const* d_in, const int* in_sizes, int n_in,
                              void* d_out, int out_size, void* d_ws, size_t ws_size,
                              hipStream_t stream)
{
    const float* x   = (const float*)d_in[0];
    const float* w1  = (const float*)d_in[1];
    const float* b1  = (const float*)d_in[2];
    const float* w2  = (const float*)d_in[3];
    const float* b2  = (const float*)d_in[4];
    const float* gam = (const float*)d_in[5];
    const float* bet = (const float*)d_in[6];
    const float* T   = (const float*)d_in[7];
    const float* lw  = (const float*)d_in[8];
    const float* lb  = (const float*)d_in[9];
    float* out = (float*)d_out;

    float* ws = (float*)d_ws;
    // Layout (float offsets):
    //   [0 .. 8,388,608)            h1 bf16 [4][64][4096][16]  -> later Mpart bf16 [2048][8192] (exact alias)
    //   [8,388,608 .. 16,777,216)   h2 fp32 (stays RAW; BN applied inline downstream)
    //   [16,777,216 .. +65,536)     Bw bf16
    //   then M (32000 f32), stats (256 f32), ob (6400 f32)
    //   then featb bf16 (4,194,304 float-slots)
    //   then bnp (2048 doubles), fpart (512 doubles)
    // Total ~84.3 MB (proven ws >= ~100.8 MB).
    __hip_bfloat16* h1 = (__hip_bfloat16*)ws;
    __hip_bfloat16* Mpart = (__hip_bfloat16*)ws;     // aliases h1 (dead after conv2)
    float* h2    = ws + 8388608;
    __hip_bfloat16* Bw = (__hip_bfloat16*)(ws + 16777216);
    float* M     = ws + 16777216 + 65536;
    float* stats = M + 32000;
    float* ob    = stats + 256;
    __hip_bfloat16* featb = (__hip_bfloat16*)(ob + 6400);
    double* bnp   = (double*)(ob + 6400 + 4194304);
    double* fpart = bnp + 2048;

    k_prepw<<<512, 256, 0, stream>>>(w2, Bw);
    k_conv1<<<1024, 256, 0, stream>>>(x, w1, b1, h1);
    k_conv2<<<512, 256, 0, stream>>>(h1, Bw, b2, h2);
    k_bnstats1<<<1024, 256, 0, stream>>>(h2, bnp);
    k_bnstats2<<<1, 128, 0, stream>>>(bnp, gam, bet, stats);
    k_bnapply<<<8192, 256, 0, stream>>>(h2, stats, featb);
    k_mgemm<<<dim3(4, KCH), 256, 0, stream>>>(featb, T, Mpart);
    k_mreduce<<<125, 256, 0, stream>>>(Mpart, M);
    k_ob<<<100, 256, 0, stream>>>(M, ob);
    k_final1<<<512, 256, 0, stream>>>(h2, stats, lw, fpart);
    k_final2<<<1, 64, 0, stream>>>(fpart, ob, lw, lb, out);
}

// Round 9
// 209.794 us; speedup vs baseline: 10.6887x; 1.5240x over previous
//
#include <hip/hip_runtime.h>
#include <hip/hip_bf16.h>
#include <math.h>

#define BB 64
#define SS 128
#define C1 64
#define H1D 64
#define C2 128
#define H2D 32
#define FLAT 131072
#define NCOL 500
#define KCH 256      // split-K chunks in mgemm (deterministic partials, bf16)
#define KCSZ 512     // k per chunk  (KCH*KCSZ == FLAT)

typedef __attribute__((ext_vector_type(4))) float f32x4;
typedef __attribute__((ext_vector_type(8))) short bf16x8;

// ---------------- conv1 (4x4 s2 p1) + leaky -> h1 bf16 [g4][b][oh][ow][16ic] ----------------
__global__ __launch_bounds__(256) void k_conv1(const float* __restrict__ x,
    const float* __restrict__ w, const float* __restrict__ bias,
    __hip_bfloat16* __restrict__ h1)
{
    int tid = blockIdx.x*256 + threadIdx.x;      // (b, oh, ow)
    int ow = tid & 63, oh = (tid>>6)&63, bi = tid>>12;
    int ih0 = oh*2-1, iw0 = ow*2-1;
    float in[48];
    #pragma unroll
    for (int ic=0; ic<3; ic++)
      #pragma unroll
      for (int kh=0; kh<4; kh++)
        #pragma unroll
        for (int kw=0; kw<4; kw++) {
          int ih = ih0+kh, iw = iw0+kw;
          float v = 0.f;
          if ((unsigned)ih < 128u && (unsigned)iw < 128u)
            v = x[((size_t)(bi*3+ic)*SS + ih)*SS + iw];
          in[ic*16+kh*4+kw] = v;
        }
    #pragma unroll
    for (int g=0; g<4; g++) {
      __hip_bfloat16 outv[16];
      #pragma unroll
      for (int ocl=0; ocl<16; ocl++) {
        int oc = g*16 + ocl;
        float a = bias[oc];
        const float* wp = w + oc*48;             // wave-uniform -> scalar loads
        #pragma unroll
        for (int t=0; t<48; t++) a = fmaf(in[t], wp[t], a);
        a = a >= 0.f ? a : 0.2f*a;
        outv[ocl] = __float2bfloat16(a);
      }
      __hip_bfloat16* dst = h1 + (((size_t)g*BB + bi)*4096 + oh*64 + ow)*16;
      *(bf16x8*)(dst)     = *(bf16x8*)&outv[0];
      *(bf16x8*)(dst + 8) = *(bf16x8*)&outv[8];
    }
}

// ---------------- weight prep: w2 fp32 -> Bw bf16 [stage4][kl8 32][oc 128][jj 8] ----------------
__global__ __launch_bounds__(256) void k_prepw(const float* __restrict__ w2,
    __hip_bfloat16* __restrict__ Bw)
{
    int i = blockIdx.x*256 + threadIdx.x;        // 131072
    int jj = i & 7, oc = (i>>3)&127, kl8 = (i>>10)&31, stage = i>>15;
    int kl = kl8*8 + jj;                         // k-local within stage: tap*16 + icl
    int tap = kl >> 4, icl = kl & 15;
    int ic = stage*16 + icl;
    Bw[i] = __float2bfloat16(w2[(size_t)oc*1024 + ic*16 + tap]);
}

// ---------------- conv2 via MFMA bf16 implicit GEMM ----------------
__global__ __launch_bounds__(256) void k_conv2(const __hip_bfloat16* __restrict__ h1,
    const __hip_bfloat16* __restrict__ Bw, const float* __restrict__ b2,
    float* __restrict__ h2)
{
    int bx = blockIdx.x;
    int nh = bx & 1, strip = (bx>>1)&3, bi = bx>>3;
    int lane = threadIdx.x & 63, wv = threadIdx.x >> 6;
    int l15 = lane & 15, kg = lane >> 4;

    __shared__ __align__(16) short tile[36*33*24];   // 1188 rows x 48B = 57 KB

    f32x4 acc[4][4];
    #pragma unroll
    for (int m=0;m<4;m++)
      #pragma unroll
      for (int n=0;n<4;n++) acc[m][n] = (f32x4)(0.f);

    int ihb = strip*16 - 1;                      // global ih of ih_l=0

    for (int stage=0; stage<4; ++stage) {
      const __hip_bfloat16* hsrc = h1 + ((size_t)stage*BB + bi)*4096*16;
      for (int idx = threadIdx.x; idx < 2376; idx += 256) {
        int half = idx & 1, p = idx >> 1;        // p = ih_l*66 + iw_l
        int ih_l = p / 66, iw_l = p - ih_l*66;
        int ih = ihb + ih_l, iw = iw_l - 1;
        int row48 = (ih_l*2 + (iw_l&1))*33 + (iw_l>>1);
        bf16x8 v = (bf16x8)(0);
        if ((unsigned)ih < 64u && (unsigned)iw < 64u)
          v = *(const bf16x8*)(hsrc + ((size_t)(ih*64+iw)*16 + half*8));
        *(bf16x8*)&tile[row48*24 + half*8] = v;
      }
      __syncthreads();
      const __hip_bfloat16* bwst = Bw + (size_t)stage*32*128*8;
      #pragma unroll
      for (int j=0; j<8; j++) {
        bf16x8 bf[4];
        #pragma unroll
        for (int nf=0; nf<4; nf++)
          bf[nf] = *(const bf16x8*)(bwst + ((size_t)((j*4+kg)*128) + nh*64 + nf*16 + l15)*8);
        int tap = 2*j + (kg>>1);
        int kh = tap>>2, kw = tap&3;
        int icl0 = (kg&1)*8;
        bf16x8 af[4];
        #pragma unroll
        for (int mf=0; mf<4; mf++) {
          int oh_l = 2*wv + (mf>>1);
          int ow   = (mf&1)*16 + l15;
          int ih_l = 2*oh_l + kh;
          int iw_l = 2*ow + kw;
          int row48 = (ih_l*2 + (iw_l&1))*33 + (iw_l>>1);
          af[mf] = *(const bf16x8*)&tile[row48*24 + icl0];
        }
        #pragma unroll
        for (int mf=0; mf<4; mf++)
          #pragma unroll
          for (int nf=0; nf<4; nf++)
            acc[mf][nf] = __builtin_amdgcn_mfma_f32_16x16x32_bf16(af[mf], bf[nf], acc[mf][nf], 0, 0, 0);
      }
      __syncthreads();
    }
    #pragma unroll
    for (int mf=0; mf<4; mf++)
      #pragma unroll
      for (int nf=0; nf<4; nf++) {
        int oc = nh*64 + nf*16 + l15;
        int p0 = wv*64 + mf*16 + kg*4;
        float bv = b2[oc];
        float4 o;
        o.x = acc[mf][nf][0] + bv;
        o.y = acc[mf][nf][1] + bv;
        o.z = acc[mf][nf][2] + bv;
        o.w = acc[mf][nf][3] + bv;
        *(float4*)&h2[((size_t)bi*C2 + oc)*1024 + strip*256 + p0] = o;
      }
}

// ---------------- batchnorm stats, 2-stage fp64 ----------------
__global__ __launch_bounds__(256) void k_bnstats1(const float* __restrict__ h2,
    double* __restrict__ bnp)
{
    int c = blockIdx.x & 127, s = blockIdx.x >> 7;
    double s1 = 0.0, s2 = 0.0;
    for (int i = threadIdx.x; i < 8*1024; i += 256) {
      int b = s*8 + (i >> 10), hw = i & 1023;
      double v = (double)h2[((size_t)b*C2 + c)*1024 + hw];
      s1 += v; s2 = fma(v, v, s2);
    }
    __shared__ double r1[256], r2[256];
    r1[threadIdx.x] = s1; r2[threadIdx.x] = s2;
    __syncthreads();
    for (int st = 128; st > 0; st >>= 1) {
      if (threadIdx.x < st) { r1[threadIdx.x] += r1[threadIdx.x+st]; r2[threadIdx.x] += r2[threadIdx.x+st]; }
      __syncthreads();
    }
    if (threadIdx.x == 0) {
      bnp[c*8 + s]        = r1[0];
      bnp[1024 + c*8 + s] = r2[0];
    }
}

__global__ void k_bnstats2(const double* __restrict__ bnp,
    const float* __restrict__ gamma, const float* __restrict__ beta,
    float* __restrict__ stats)
{
    int c = threadIdx.x;   // 128 threads, 1 block
    double s1 = 0.0, s2 = 0.0;
    #pragma unroll
    for (int s = 0; s < 8; s++) { s1 += bnp[c*8+s]; s2 += bnp[1024 + c*8+s]; }
    double mean = s1 * (1.0/65536.0);
    double var  = s2 * (1.0/65536.0) - mean*mean;
    double rstd = 1.0 / sqrt(var + 1e-5);
    double sc = rstd * (double)gamma[c];
    stats[c]      = (float)sc;
    stats[C2 + c] = (float)((double)beta[c] - mean*sc);
}

// ---------------- BN apply + leaky -> featb (bf16 only; h2 stays raw) ----------------
__global__ __launch_bounds__(256) void k_bnapply(const float* __restrict__ h2,
    const float* __restrict__ stats, __hip_bfloat16* __restrict__ featb)
{
    int i = blockIdx.x*256 + threadIdx.x;       // float4 index
    int c = (i >> 8) & 127;
    float sc = stats[c], sh = stats[C2 + c];
    float4 v = ((const float4*)h2)[i];
    float4 o;
    o.x = fmaf(v.x, sc, sh); o.x = o.x >= 0.f ? o.x : 0.2f*o.x;
    o.y = fmaf(v.y, sc, sh); o.y = o.y >= 0.f ? o.y : 0.2f*o.y;
    o.z = fmaf(v.z, sc, sh); o.z = o.z >= 0.f ? o.z : 0.2f*o.z;
    o.w = fmaf(v.w, sc, sh); o.w = o.w >= 0.f ? o.w : 0.2f*o.w;
    __hip_bfloat16 b[4];
    b[0] = __float2bfloat16(o.x); b[1] = __float2bfloat16(o.y);
    b[2] = __float2bfloat16(o.z); b[3] = __float2bfloat16(o.w);
    *(double*)(featb + (size_t)i*4) = *(double*)b;   // 8B store
}

// ---------------- M = featb @ T via MFMA, LDS-staged T (deterministic split-K) ----------------
// 1024 blocks (1D, XCD-swizzled so the 4 col-groups of one kc share an XCD L2).
// Block: 4 waves, 128 cols (ng), 512 k (kc).  Per 32-k step: stage T[32][128]
// fp32 -> LDS (float4 loads, 16B/lane in flight; fixes the scalar-load
// vmcnt-limited ~3.4 TB/s ceiling of R5-R7), double-buffered, T14 split
// (issue loads -> compute -> write).  B-frags: 8x ds_read_b32 + cvt (pad 134
// -> 2-way conflicts = free).  Partials: thread-order bf16 (1KB/wave stores).
__global__ __launch_bounds__(256) void k_mgemm(const __hip_bfloat16* __restrict__ featb,
    const float* __restrict__ T, __hip_bfloat16* __restrict__ Mpart)
{
    int t = threadIdx.x;
    int lane = t & 63, wv = t >> 6;
    int l15 = lane & 15, kg = lane >> 4;
    // XCD swizzle: x = bid&7 (round-robin XCD), j = bid>>3; kc = x*32 + j/4, ng = j&3
    int bid = blockIdx.x;
    int xc = bid & 7, j = bid >> 3;
    int kc = xc*32 + (j >> 2);
    int ng = j & 3;
    int k0b = kc * KCSZ;

    __shared__ float Ts[2][32][134];   // 34.3 KB -> 4 blocks/CU

    int f4c = t & 31, rbase = t >> 5;          // staging coords
    int cols4 = ng*128 + f4c*4;
    bool cvalid = cols4 < 500;

    f32x4 acc[4][2];
    #pragma unroll
    for (int m=0;m<4;m++) { acc[m][0] = (f32x4)(0.f); acc[m][1] = (f32x4)(0.f); }

    float4 tv0, tv1, tv2, tv3;                 // staged regs (named: rule #20)
    // ---- prologue: load + write step 0
    {
      int ks0 = k0b;
      tv0 = cvalid ? *(const float4*)&T[(size_t)(ks0+rbase   )*NCOL + cols4] : make_float4(0,0,0,0);
      tv1 = cvalid ? *(const float4*)&T[(size_t)(ks0+rbase+ 8)*NCOL + cols4] : make_float4(0,0,0,0);
      tv2 = cvalid ? *(const float4*)&T[(size_t)(ks0+rbase+16)*NCOL + cols4] : make_float4(0,0,0,0);
      tv3 = cvalid ? *(const float4*)&T[(size_t)(ks0+rbase+24)*NCOL + cols4] : make_float4(0,0,0,0);
      float* d0 = &Ts[0][rbase   ][f4c*4];
      float* d1 = &Ts[0][rbase+ 8][f4c*4];
      float* d2 = &Ts[0][rbase+16][f4c*4];
      float* d3 = &Ts[0][rbase+24][f4c*4];
      *(float2*)d0 = make_float2(tv0.x,tv0.y); *(float2*)(d0+2) = make_float2(tv0.z,tv0.w);
      *(float2*)d1 = make_float2(tv1.x,tv1.y); *(float2*)(d1+2) = make_float2(tv1.z,tv1.w);
      *(float2*)d2 = make_float2(tv2.x,tv2.y); *(float2*)(d2+2) = make_float2(tv2.z,tv2.w);
      *(float2*)d3 = make_float2(tv3.x,tv3.y); *(float2*)(d3+2) = make_float2(tv3.z,tv3.w);
    }
    __syncthreads();

    for (int s = 0; s < 16; s++) {
      int cur = s & 1;
      // issue next-step global loads (latency hidden under compute below)
      if (s < 15) {
        int ks0 = k0b + (s+1)*32;
        tv0 = cvalid ? *(const float4*)&T[(size_t)(ks0+rbase   )*NCOL + cols4] : make_float4(0,0,0,0);
        tv1 = cvalid ? *(const float4*)&T[(size_t)(ks0+rbase+ 8)*NCOL + cols4] : make_float4(0,0,0,0);
        tv2 = cvalid ? *(const float4*)&T[(size_t)(ks0+rbase+16)*NCOL + cols4] : make_float4(0,0,0,0);
        tv3 = cvalid ? *(const float4*)&T[(size_t)(ks0+rbase+24)*NCOL + cols4] : make_float4(0,0,0,0);
      }
      // compute on buffer cur
      {
        int k0 = k0b + s*32;
        bf16x8 af[4];
        #pragma unroll
        for (int mf=0; mf<4; mf++)
          af[mf] = *(const bf16x8*)(featb + (size_t)(mf*16 + l15)*FLAT + k0 + kg*8);
        bf16x8 bfr[2];
        #pragma unroll
        for (int nf=0; nf<2; nf++) {
          int c = wv*32 + nf*16 + l15;
          __hip_bfloat16 tb[8];
          #pragma unroll
          for (int jj=0; jj<8; jj++)
            tb[jj] = __float2bfloat16(Ts[cur][kg*8+jj][c]);
          bfr[nf] = *(bf16x8*)tb;
        }
        #pragma unroll
        for (int mf=0;mf<4;mf++)
          #pragma unroll
          for (int nf=0;nf<2;nf++)
            acc[mf][nf] = __builtin_amdgcn_mfma_f32_16x16x32_bf16(af[mf], bfr[nf], acc[mf][nf], 0, 0, 0);
      }
      __syncthreads();
      if (s < 15) {
        int nb = cur ^ 1;
        float* d0 = &Ts[nb][rbase   ][f4c*4];
        float* d1 = &Ts[nb][rbase+ 8][f4c*4];
        float* d2 = &Ts[nb][rbase+16][f4c*4];
        float* d3 = &Ts[nb][rbase+24][f4c*4];
        *(float2*)d0 = make_float2(tv0.x,tv0.y); *(float2*)(d0+2) = make_float2(tv0.z,tv0.w);
        *(float2*)d1 = make_float2(tv1.x,tv1.y); *(float2*)(d1+2) = make_float2(tv1.z,tv1.w);
        *(float2*)d2 = make_float2(tv2.x,tv2.y); *(float2*)(d2+2) = make_float2(tv2.z,tv2.w);
        *(float2*)d3 = make_float2(tv3.x,tv3.y); *(float2*)(d3+2) = make_float2(tv3.z,tv3.w);
        __syncthreads();
      }
    }
    // thread-order coalesced store: Mpart[(kc*4+ng)][mf][t][nf*4+q]
    __hip_bfloat16* op = Mpart + (size_t)(kc*4 + ng)*8192;
    #pragma unroll
    for (int mf=0; mf<4; mf++) {
      __hip_bfloat16 buf[8];
      #pragma unroll
      for (int nf=0; nf<2; nf++)
        #pragma unroll
        for (int q=0; q<4; q++)
          buf[nf*4+q] = __float2bfloat16(acc[mf][nf][q]);
      *(bf16x8*)(op + ((size_t)mf*256 + t)*8) = *(bf16x8*)buf;
    }
}

// inverts the thread-order layout: r=mf*16+kg*4+q, c=ng*128+wv*32+nf*16+l15
__global__ __launch_bounds__(256) void k_mreduce(const __hip_bfloat16* __restrict__ Mpart,
    float* __restrict__ M)
{
    int i = blockIdx.x*256 + threadIdx.x;   // 32000 = 64*500
    int r = i / NCOL, c = i - r*NCOL;
    int mf = r >> 4, kg = (r >> 2) & 3, q = r & 3;
    int ng = c >> 7, wv = (c >> 5) & 3, nf = (c >> 4) & 1, l15 = c & 15;
    int t = wv*64 + kg*16 + l15;
    const __hip_bfloat16* p = Mpart + ((size_t)ng*1024 + mf*256 + t)*8 + nf*4 + q;
    float s = 0.f;
    #pragma unroll 8
    for (int kc = 0; kc < KCH; kc++) s += __bfloat162float(p[(size_t)kc*32768]);
    M[i] = s;
}

// ---------------- minibatch discrimination: o_b ----------------
__global__ __launch_bounds__(256) void k_ob(const float* __restrict__ M,
    float* __restrict__ ob)
{
    int o = blockIdx.x;   // 0..99
    __shared__ float Ms[320];
    __shared__ float red[256];
    for (int idx = threadIdx.x; idx < 320; idx += 256) {
      int a = idx / 5, d = idx - a*5;
      Ms[idx] = M[(size_t)a*NCOL + o*5 + d];
    }
    __syncthreads();
    int b = threadIdx.x & 63, aq = threadIdx.x >> 6;
    float s = 0.f;
    for (int a = aq*16; a < aq*16+16; a++) {
      float n = 0.f;
      #pragma unroll
      for (int d=0; d<5; d++) n += fabsf(Ms[a*5+d] - Ms[b*5+d]);
      s += expf(-n);
    }
    red[threadIdx.x] = s;
    __syncthreads();
    if (threadIdx.x < 64)
      ob[(size_t)b*100 + o] = red[b] + red[64+b] + red[128+b] + red[192+b];
}

// ---------------- final linear: stage1 partial dots (BN applied inline from raw h2) ----------------
__global__ __launch_bounds__(256) void k_final1(const float* __restrict__ h2,
    const float* __restrict__ stats, const float* __restrict__ lw,
    double* __restrict__ fpart)
{
    int bx = blockIdx.x;          // 512 = b*8 + s
    int b = bx >> 3, s = bx & 7;
    const float4* fp = (const float4*)(h2 + (size_t)b*FLAT);
    const float4* wp = (const float4*)lw;
    double acc = 0.0;
    for (int j = s*4096 + threadIdx.x; j < (s+1)*4096; j += 256) {
      int c = (j >> 8) & 127;
      float sc = stats[c], sh = stats[C2 + c];
      float4 v = fp[j], w = wp[j];
      float4 o;
      o.x = fmaf(v.x, sc, sh); o.x = o.x >= 0.f ? o.x : 0.2f*o.x;
      o.y = fmaf(v.y, sc, sh); o.y = o.y >= 0.f ? o.y : 0.2f*o.y;
      o.z = fmaf(v.z, sc, sh); o.z = o.z >= 0.f ? o.z : 0.2f*o.z;
      o.w = fmaf(v.w, sc, sh); o.w = o.w >= 0.f ? o.w : 0.2f*o.w;
      acc = fma((double)o.x, (double)w.x, acc);
      acc = fma((double)o.y, (double)w.y, acc);
      acc = fma((double)o.z, (double)w.z, acc);
      acc = fma((double)o.w, (double)w.w, acc);
    }
    __shared__ double red[256];
    red[threadIdx.x] = acc;
    __syncthreads();
    for (int st = 128; st > 0; st >>= 1) {
      if (threadIdx.x < st) red[threadIdx.x] += red[threadIdx.x + st];
      __syncthreads();
    }
    if (threadIdx.x == 0) fpart[bx] = red[0];
}

__global__ void k_final2(const double* __restrict__ fpart,
    const float* __restrict__ ob, const float* __restrict__ lw,
    const float* __restrict__ lb, float* __restrict__ out)
{
    int b = threadIdx.x;   // 64 threads, 1 block
    double s = 0.0;
    #pragma unroll
    for (int i = 0; i < 8; i++) s += fpart[b*8 + i];
    for (int o = 0; o < 100; o++)
      s = fma((double)ob[(size_t)b*100 + o], (double)lw[FLAT + o], s);
    s += (double)lb[0];
    out[b] = (float)(1.0 / (1.0 + exp(-s)));
}

extern "C" void kernel_launch(void* const* d_in, const int* in_sizes, int n_in,
                              void* d_out, int out_size, void* d_ws, size_t ws_size,
                              hipStream_t stream)
{
    const float* x   = (const float*)d_in[0];
    const float* w1  = (const float*)d_in[1];
    const float* b1  = (const float*)d_in[2];
    const float* w2  = (const float*)d_in[3];
    const float* b2  = (const float*)d_in[4];
    const float* gam = (const float*)d_in[5];
    const float* bet = (const float*)d_in[6];
    const float* T   = (const float*)d_in[7];
    const float* lw  = (const float*)d_in[8];
    const float* lb  = (const float*)d_in[9];
    float* out = (float*)d_out;

    float* ws = (float*)d_ws;
    // Layout (float offsets):
    //   [0 .. 8,388,608)            h1 bf16 [4][64][4096][16]  -> later Mpart bf16 [1024][8192] (16.8MB)
    //   [8,388,608 .. 16,777,216)   h2 fp32 (stays RAW; BN applied inline downstream)
    //   [16,777,216 .. +65,536)     Bw bf16
    //   then M (32000 f32), stats (256 f32), ob (6400 f32)
    //   then featb bf16 (4,194,304 float-slots)
    //   then bnp (2048 doubles), fpart (512 doubles)
    // Total ~84.3 MB (proven ws >= ~100.8 MB).
    __hip_bfloat16* h1 = (__hip_bfloat16*)ws;
    __hip_bfloat16* Mpart = (__hip_bfloat16*)ws;     // aliases h1 (dead after conv2)
    float* h2    = ws + 8388608;
    __hip_bfloat16* Bw = (__hip_bfloat16*)(ws + 16777216);
    float* M     = ws + 16777216 + 65536;
    float* stats = M + 32000;
    float* ob    = stats + 256;
    __hip_bfloat16* featb = (__hip_bfloat16*)(ob + 6400);
    double* bnp   = (double*)(ob + 6400 + 4194304);
    double* fpart = bnp + 2048;

    k_prepw<<<512, 256, 0, stream>>>(w2, Bw);
    k_conv1<<<1024, 256, 0, stream>>>(x, w1, b1, h1);
    k_conv2<<<512, 256, 0, stream>>>(h1, Bw, b2, h2);
    k_bnstats1<<<1024, 256, 0, stream>>>(h2, bnp);
    k_bnstats2<<<1, 128, 0, stream>>>(bnp, gam, bet, stats);
    k_bnapply<<<8192, 256, 0, stream>>>(h2, stats, featb);
    k_mgemm<<<1024, 256, 0, stream>>>(featb, T, Mpart);
    k_mreduce<<<125, 256, 0, stream>>>(Mpart, M);
    k_ob<<<100, 256, 0, stream>>>(M, ob);
    k_final1<<<512, 256, 0, stream>>>(h2, stats, lw, fpart);
    k_final2<<<1, 64, 0, stream>>>(fpart, ob, lw, lb, out);
}

// Round 10
// 178.808 us; speedup vs baseline: 12.5410x; 1.1733x over previous
//
#include <hip/hip_runtime.h>
#include <hip/hip_bf16.h>
#include <math.h>

#define BB 64
#define SS 128
#define C1 64
#define H1D 64
#define C2 128
#define H2D 32
#define FLAT 131072
#define NCOL 500
#define KCH 256      // split-K chunks in mgemm (deterministic partials, bf16)
#define KCSZ 512     // k per chunk  (KCH*KCSZ == FLAT)

typedef __attribute__((ext_vector_type(4))) float f32x4;
typedef __attribute__((ext_vector_type(8))) short bf16x8;

__device__ inline float bf2f(short s) {
    union { unsigned int u; float f; } z;
    z.u = ((unsigned int)(unsigned short)s) << 16;
    return z.f;
}

// BN scale/shift for channel c from fp64 partial sums bnp[ c*8+s | 1024+c*8+s ]
__device__ inline void bn_coeff(const double* __restrict__ bnp,
    const float* __restrict__ gamma, const float* __restrict__ beta,
    int c, float& sc, float& sh)
{
    double s1 = 0.0, s2 = 0.0;
    #pragma unroll
    for (int s = 0; s < 8; s++) { s1 += bnp[c*8+s]; s2 += bnp[1024 + c*8+s]; }
    double mean = s1 * (1.0/65536.0);
    double var  = s2 * (1.0/65536.0) - mean*mean;
    double rstd = 1.0 / sqrt(var + 1e-5);
    double scd  = rstd * (double)gamma[c];
    sc = (float)scd;
    sh = (float)((double)beta[c] - mean*scd);
}

// ---------------- fused: prepw (blocks 0..511) + conv1 (blocks 512..1535) ----------------
// conv1 (4x4 s2 p1) + leaky -> h1 bf16 [g4][b][oh][ow][16ic]
// prepw: w2 fp32 -> Bw bf16 [stage4][kl8 32][oc 128][jj 8]
__global__ __launch_bounds__(256) void k_conv1p(const float* __restrict__ x,
    const float* __restrict__ w, const float* __restrict__ bias,
    const float* __restrict__ w2,
    __hip_bfloat16* __restrict__ h1, __hip_bfloat16* __restrict__ Bw)
{
    int bid = blockIdx.x;
    if (bid < 512) {
      int i = bid*256 + threadIdx.x;             // 131072
      int jj = i & 7, oc = (i>>3)&127, kl8 = (i>>10)&31, stage = i>>15;
      int kl = kl8*8 + jj;
      int tap = kl >> 4, icl = kl & 15;
      int ic = stage*16 + icl;
      Bw[i] = __float2bfloat16(w2[(size_t)oc*1024 + ic*16 + tap]);
      return;
    }
    int tid = (bid - 512)*256 + threadIdx.x;     // (b, oh, ow)
    int ow = tid & 63, oh = (tid>>6)&63, bi = tid>>12;
    int ih0 = oh*2-1, iw0 = ow*2-1;
    float in[48];
    #pragma unroll
    for (int ic=0; ic<3; ic++)
      #pragma unroll
      for (int kh=0; kh<4; kh++)
        #pragma unroll
        for (int kw=0; kw<4; kw++) {
          int ih = ih0+kh, iw = iw0+kw;
          float v = 0.f;
          if ((unsigned)ih < 128u && (unsigned)iw < 128u)
            v = x[((size_t)(bi*3+ic)*SS + ih)*SS + iw];
          in[ic*16+kh*4+kw] = v;
        }
    #pragma unroll
    for (int g=0; g<4; g++) {
      __hip_bfloat16 outv[16];
      #pragma unroll
      for (int ocl=0; ocl<16; ocl++) {
        int oc = g*16 + ocl;
        float a = bias[oc];
        const float* wp = w + oc*48;             // wave-uniform -> scalar loads
        #pragma unroll
        for (int t=0; t<48; t++) a = fmaf(in[t], wp[t], a);
        a = a >= 0.f ? a : 0.2f*a;
        outv[ocl] = __float2bfloat16(a);
      }
      __hip_bfloat16* dst = h1 + (((size_t)g*BB + bi)*4096 + oh*64 + ow)*16;
      *(bf16x8*)(dst)     = *(bf16x8*)&outv[0];
      *(bf16x8*)(dst + 8) = *(bf16x8*)&outv[8];
    }
}

// ---------------- conv2 via MFMA bf16 implicit GEMM -> h2b bf16 [b][c*1024+hw] ----------------
__global__ __launch_bounds__(256) void k_conv2(const __hip_bfloat16* __restrict__ h1,
    const __hip_bfloat16* __restrict__ Bw, const float* __restrict__ b2,
    __hip_bfloat16* __restrict__ h2b)
{
    int bx = blockIdx.x;
    int nh = bx & 1, strip = (bx>>1)&3, bi = bx>>3;
    int lane = threadIdx.x & 63, wv = threadIdx.x >> 6;
    int l15 = lane & 15, kg = lane >> 4;

    __shared__ __align__(16) short tile[36*33*24];   // 1188 rows x 48B = 57 KB

    f32x4 acc[4][4];
    #pragma unroll
    for (int m=0;m<4;m++)
      #pragma unroll
      for (int n=0;n<4;n++) acc[m][n] = (f32x4)(0.f);

    int ihb = strip*16 - 1;

    for (int stage=0; stage<4; ++stage) {
      const __hip_bfloat16* hsrc = h1 + ((size_t)stage*BB + bi)*4096*16;
      for (int idx = threadIdx.x; idx < 2376; idx += 256) {
        int half = idx & 1, p = idx >> 1;        // p = ih_l*66 + iw_l
        int ih_l = p / 66, iw_l = p - ih_l*66;
        int ih = ihb + ih_l, iw = iw_l - 1;
        int row48 = (ih_l*2 + (iw_l&1))*33 + (iw_l>>1);
        bf16x8 v = (bf16x8)(0);
        if ((unsigned)ih < 64u && (unsigned)iw < 64u)
          v = *(const bf16x8*)(hsrc + ((size_t)(ih*64+iw)*16 + half*8));
        *(bf16x8*)&tile[row48*24 + half*8] = v;
      }
      __syncthreads();
      const __hip_bfloat16* bwst = Bw + (size_t)stage*32*128*8;
      #pragma unroll
      for (int j=0; j<8; j++) {
        bf16x8 bf[4];
        #pragma unroll
        for (int nf=0; nf<4; nf++)
          bf[nf] = *(const bf16x8*)(bwst + ((size_t)((j*4+kg)*128) + nh*64 + nf*16 + l15)*8);
        int tap = 2*j + (kg>>1);
        int kh = tap>>2, kw = tap&3;
        int icl0 = (kg&1)*8;
        bf16x8 af[4];
        #pragma unroll
        for (int mf=0; mf<4; mf++) {
          int oh_l = 2*wv + (mf>>1);
          int ow   = (mf&1)*16 + l15;
          int ih_l = 2*oh_l + kh;
          int iw_l = 2*ow + kw;
          int row48 = (ih_l*2 + (iw_l&1))*33 + (iw_l>>1);
          af[mf] = *(const bf16x8*)&tile[row48*24 + icl0];
        }
        #pragma unroll
        for (int mf=0; mf<4; mf++)
          #pragma unroll
          for (int nf=0; nf<4; nf++)
            acc[mf][nf] = __builtin_amdgcn_mfma_f32_16x16x32_bf16(af[mf], bf[nf], acc[mf][nf], 0, 0, 0);
      }
      __syncthreads();
    }
    #pragma unroll
    for (int mf=0; mf<4; mf++)
      #pragma unroll
      for (int nf=0; nf<4; nf++) {
        int oc = nh*64 + nf*16 + l15;
        int p0 = wv*64 + mf*16 + kg*4;
        float bv = b2[oc];
        __hip_bfloat16 o4[4];
        o4[0] = __float2bfloat16(acc[mf][nf][0] + bv);
        o4[1] = __float2bfloat16(acc[mf][nf][1] + bv);
        o4[2] = __float2bfloat16(acc[mf][nf][2] + bv);
        o4[3] = __float2bfloat16(acc[mf][nf][3] + bv);
        *(double*)&h2b[((size_t)bi*C2 + oc)*1024 + strip*256 + p0] = *(double*)o4;
      }
}

// ---------------- batchnorm stats stage1 (fp64 partials; bf16 input) ----------------
__global__ __launch_bounds__(256) void k_bnstats1(const __hip_bfloat16* __restrict__ h2b,
    double* __restrict__ bnp)
{
    int c = blockIdx.x & 127, s = blockIdx.x >> 7;
    double s1 = 0.0, s2 = 0.0;
    for (int g = threadIdx.x; g < 1024; g += 256) {      // bf16x8 groups
      int b = s*8 + (g >> 7), hw8 = g & 127;
      bf16x8 v = *(const bf16x8*)&h2b[((size_t)b*C2 + c)*1024 + hw8*8];
      #pragma unroll
      for (int j=0;j<8;j++) {
        double f = (double)bf2f(v[j]);
        s1 += f; s2 = fma(f, f, s2);
      }
    }
    __shared__ double r1[256], r2[256];
    r1[threadIdx.x] = s1; r2[threadIdx.x] = s2;
    __syncthreads();
    for (int st = 128; st > 0; st >>= 1) {
      if (threadIdx.x < st) { r1[threadIdx.x] += r1[threadIdx.x+st]; r2[threadIdx.x] += r2[threadIdx.x+st]; }
      __syncthreads();
    }
    if (threadIdx.x == 0) {
      bnp[c*8 + s]        = r1[0];
      bnp[1024 + c*8 + s] = r2[0];
    }
}

// ---------------- M = BN(h2b) @ T via MFMA, LDS-staged T, BN inline ----------------
// 1024 blocks (XCD-swizzled).  kc spans 512 k = half of ONE channel -> per-block
// uniform (sc,sh) computed from bnp.  A-frags: bf16 h2b -> BN+leaky -> bf16.
__global__ __launch_bounds__(256) void k_mgemm(const __hip_bfloat16* __restrict__ h2b,
    const double* __restrict__ bnp, const float* __restrict__ gamma,
    const float* __restrict__ beta, const float* __restrict__ T,
    __hip_bfloat16* __restrict__ Mpart)
{
    int t = threadIdx.x;
    int lane = t & 63, wv = t >> 6;
    int l15 = lane & 15, kg = lane >> 4;
    int bid = blockIdx.x;
    int xc = bid & 7, j = bid >> 3;
    int kc = xc*32 + (j >> 2);
    int ng = j & 3;
    int k0b = kc * KCSZ;

    float sc, sh;
    bn_coeff(bnp, gamma, beta, kc >> 1, sc, sh);

    __shared__ float Ts[2][32][134];   // 34.3 KB

    int f4c = t & 31, rbase = t >> 5;
    int cols4 = ng*128 + f4c*4;
    bool cvalid = cols4 < 500;

    f32x4 acc[4][2];
    #pragma unroll
    for (int m=0;m<4;m++) { acc[m][0] = (f32x4)(0.f); acc[m][1] = (f32x4)(0.f); }

    float4 tv0, tv1, tv2, tv3;
    {
      int ks0 = k0b;
      tv0 = cvalid ? *(const float4*)&T[(size_t)(ks0+rbase   )*NCOL + cols4] : make_float4(0,0,0,0);
      tv1 = cvalid ? *(const float4*)&T[(size_t)(ks0+rbase+ 8)*NCOL + cols4] : make_float4(0,0,0,0);
      tv2 = cvalid ? *(const float4*)&T[(size_t)(ks0+rbase+16)*NCOL + cols4] : make_float4(0,0,0,0);
      tv3 = cvalid ? *(const float4*)&T[(size_t)(ks0+rbase+24)*NCOL + cols4] : make_float4(0,0,0,0);
      float* d0 = &Ts[0][rbase   ][f4c*4];
      float* d1 = &Ts[0][rbase+ 8][f4c*4];
      float* d2 = &Ts[0][rbase+16][f4c*4];
      float* d3 = &Ts[0][rbase+24][f4c*4];
      *(float2*)d0 = make_float2(tv0.x,tv0.y); *(float2*)(d0+2) = make_float2(tv0.z,tv0.w);
      *(float2*)d1 = make_float2(tv1.x,tv1.y); *(float2*)(d1+2) = make_float2(tv1.z,tv1.w);
      *(float2*)d2 = make_float2(tv2.x,tv2.y); *(float2*)(d2+2) = make_float2(tv2.z,tv2.w);
      *(float2*)d3 = make_float2(tv3.x,tv3.y); *(float2*)(d3+2) = make_float2(tv3.z,tv3.w);
    }
    __syncthreads();

    for (int s = 0; s < 16; s++) {
      int cur = s & 1;
      if (s < 15) {
        int ks0 = k0b + (s+1)*32;
        tv0 = cvalid ? *(const float4*)&T[(size_t)(ks0+rbase   )*NCOL + cols4] : make_float4(0,0,0,0);
        tv1 = cvalid ? *(const float4*)&T[(size_t)(ks0+rbase+ 8)*NCOL + cols4] : make_float4(0,0,0,0);
        tv2 = cvalid ? *(const float4*)&T[(size_t)(ks0+rbase+16)*NCOL + cols4] : make_float4(0,0,0,0);
        tv3 = cvalid ? *(const float4*)&T[(size_t)(ks0+rbase+24)*NCOL + cols4] : make_float4(0,0,0,0);
      }
      {
        int k0 = k0b + s*32;
        bf16x8 af[4];
        #pragma unroll
        for (int mf=0; mf<4; mf++) {
          bf16x8 raw = *(const bf16x8*)(h2b + (size_t)(mf*16 + l15)*FLAT + k0 + kg*8);
          __hip_bfloat16 ta[8];
          #pragma unroll
          for (int jj=0; jj<8; jj++) {
            float f = fmaf(bf2f(raw[jj]), sc, sh);
            f = f >= 0.f ? f : 0.2f*f;
            ta[jj] = __float2bfloat16(f);
          }
          af[mf] = *(bf16x8*)ta;
        }
        bf16x8 bfr[2];
        #pragma unroll
        for (int nf=0; nf<2; nf++) {
          int c = wv*32 + nf*16 + l15;
          __hip_bfloat16 tb[8];
          #pragma unroll
          for (int jj=0; jj<8; jj++)
            tb[jj] = __float2bfloat16(Ts[cur][kg*8+jj][c]);
          bfr[nf] = *(bf16x8*)tb;
        }
        #pragma unroll
        for (int mf=0;mf<4;mf++)
          #pragma unroll
          for (int nf=0;nf<2;nf++)
            acc[mf][nf] = __builtin_amdgcn_mfma_f32_16x16x32_bf16(af[mf], bfr[nf], acc[mf][nf], 0, 0, 0);
      }
      __syncthreads();
      if (s < 15) {
        int nb = cur ^ 1;
        float* d0 = &Ts[nb][rbase   ][f4c*4];
        float* d1 = &Ts[nb][rbase+ 8][f4c*4];
        float* d2 = &Ts[nb][rbase+16][f4c*4];
        float* d3 = &Ts[nb][rbase+24][f4c*4];
        *(float2*)d0 = make_float2(tv0.x,tv0.y); *(float2*)(d0+2) = make_float2(tv0.z,tv0.w);
        *(float2*)d1 = make_float2(tv1.x,tv1.y); *(float2*)(d1+2) = make_float2(tv1.z,tv1.w);
        *(float2*)d2 = make_float2(tv2.x,tv2.y); *(float2*)(d2+2) = make_float2(tv2.z,tv2.w);
        *(float2*)d3 = make_float2(tv3.x,tv3.y); *(float2*)(d3+2) = make_float2(tv3.z,tv3.w);
        __syncthreads();
      }
    }
    // thread-order coalesced store: Mpart[(kc*4+ng)][mf][t][nf*4+q]
    __hip_bfloat16* op = Mpart + (size_t)(kc*4 + ng)*8192;
    #pragma unroll
    for (int mf=0; mf<4; mf++) {
      __hip_bfloat16 buf[8];
      #pragma unroll
      for (int nf=0; nf<2; nf++)
        #pragma unroll
        for (int q=0; q<4; q++)
          buf[nf*4+q] = __float2bfloat16(acc[mf][nf][q]);
      *(bf16x8*)(op + ((size_t)mf*256 + t)*8) = *(bf16x8*)buf;
    }
}

// inverts the thread-order layout: r=mf*16+kg*4+q, c=ng*128+wv*32+nf*16+l15
__global__ __launch_bounds__(256) void k_mreduce(const __hip_bfloat16* __restrict__ Mpart,
    float* __restrict__ M)
{
    int i = blockIdx.x*256 + threadIdx.x;   // 32000 = 64*500
    int r = i / NCOL, c = i - r*NCOL;
    int mf = r >> 4, kg = (r >> 2) & 3, q = r & 3;
    int ng = c >> 7, wv = (c >> 5) & 3, nf = (c >> 4) & 1, l15 = c & 15;
    int t = wv*64 + kg*16 + l15;
    const __hip_bfloat16* p = Mpart + ((size_t)ng*1024 + mf*256 + t)*8 + nf*4 + q;
    float s = 0.f;
    #pragma unroll 8
    for (int kc = 0; kc < KCH; kc++) s += __bfloat162float(p[(size_t)kc*32768]);
    M[i] = s;
}

// ---------------- minibatch discrimination: o_b ----------------
__global__ __launch_bounds__(256) void k_ob(const float* __restrict__ M,
    float* __restrict__ ob)
{
    int o = blockIdx.x;   // 0..99
    __shared__ float Ms[320];
    __shared__ float red[256];
    for (int idx = threadIdx.x; idx < 320; idx += 256) {
      int a = idx / 5, d = idx - a*5;
      Ms[idx] = M[(size_t)a*NCOL + o*5 + d];
    }
    __syncthreads();
    int b = threadIdx.x & 63, aq = threadIdx.x >> 6;
    float s = 0.f;
    for (int a = aq*16; a < aq*16+16; a++) {
      float n = 0.f;
      #pragma unroll
      for (int d=0; d<5; d++) n += fabsf(Ms[a*5+d] - Ms[b*5+d]);
      s += expf(-n);
    }
    red[threadIdx.x] = s;
    __syncthreads();
    if (threadIdx.x < 64)
      ob[(size_t)b*100 + o] = red[b] + red[64+b] + red[128+b] + red[192+b];
}

// ---------------- final linear stage1: BN inline from bf16 h2b, fp64 partial dots ----------------
__global__ __launch_bounds__(256) void k_final1(const __hip_bfloat16* __restrict__ h2b,
    const double* __restrict__ bnp, const float* __restrict__ gamma,
    const float* __restrict__ beta, const float* __restrict__ lw,
    double* __restrict__ fpart)
{
    int bx = blockIdx.x;          // 512 = b*8 + s
    int b = bx >> 3, s = bx & 7;
    __shared__ float scs[16], shs[16];
    if (threadIdx.x < 16) {
      float sc, sh;
      bn_coeff(bnp, gamma, beta, s*16 + threadIdx.x, sc, sh);
      scs[threadIdx.x] = sc; shs[threadIdx.x] = sh;
    }
    __syncthreads();
    const __hip_bfloat16* hp = h2b + (size_t)b*FLAT;
    double acc = 0.0;
    for (int g = s*2048 + threadIdx.x; g < (s+1)*2048; g += 256) {  // bf16x8 groups
      int k = g*8;
      int cl = (k >> 10) & 15;
      float sc = scs[cl], sh = shs[cl];
      bf16x8 v = *(const bf16x8*)&hp[k];
      float4 w0 = *(const float4*)&lw[k];
      float4 w1 = *(const float4*)&lw[k+4];
      float f0 = fmaf(bf2f(v[0]), sc, sh); f0 = f0>=0.f?f0:0.2f*f0;
      float f1 = fmaf(bf2f(v[1]), sc, sh); f1 = f1>=0.f?f1:0.2f*f1;
      float f2 = fmaf(bf2f(v[2]), sc, sh); f2 = f2>=0.f?f2:0.2f*f2;
      float f3 = fmaf(bf2f(v[3]), sc, sh); f3 = f3>=0.f?f3:0.2f*f3;
      float f4 = fmaf(bf2f(v[4]), sc, sh); f4 = f4>=0.f?f4:0.2f*f4;
      float f5 = fmaf(bf2f(v[5]), sc, sh); f5 = f5>=0.f?f5:0.2f*f5;
      float f6 = fmaf(bf2f(v[6]), sc, sh); f6 = f6>=0.f?f6:0.2f*f6;
      float f7 = fmaf(bf2f(v[7]), sc, sh); f7 = f7>=0.f?f7:0.2f*f7;
      acc = fma((double)f0, (double)w0.x, acc);
      acc = fma((double)f1, (double)w0.y, acc);
      acc = fma((double)f2, (double)w0.z, acc);
      acc = fma((double)f3, (double)w0.w, acc);
      acc = fma((double)f4, (double)w1.x, acc);
      acc = fma((double)f5, (double)w1.y, acc);
      acc = fma((double)f6, (double)w1.z, acc);
      acc = fma((double)f7, (double)w1.w, acc);
    }
    __shared__ double red[256];
    red[threadIdx.x] = acc;
    __syncthreads();
    for (int st = 128; st > 0; st >>= 1) {
      if (threadIdx.x < st) red[threadIdx.x] += red[threadIdx.x + st];
      __syncthreads();
    }
    if (threadIdx.x == 0) fpart[bx] = red[0];
}

__global__ void k_final2(const double* __restrict__ fpart,
    const float* __restrict__ ob, const float* __restrict__ lw,
    const float* __restrict__ lb, float* __restrict__ out)
{
    int b = threadIdx.x;   // 64 threads, 1 block
    double s = 0.0;
    #pragma unroll
    for (int i = 0; i < 8; i++) s += fpart[b*8 + i];
    for (int o = 0; o < 100; o++)
      s = fma((double)ob[(size_t)b*100 + o], (double)lw[FLAT + o], s);
    s += (double)lb[0];
    out[b] = (float)(1.0 / (1.0 + exp(-s)));
}

extern "C" void kernel_launch(void* const* d_in, const int* in_sizes, int n_in,
                              void* d_out, int out_size, void* d_ws, size_t ws_size,
                              hipStream_t stream)
{
    const float* x   = (const float*)d_in[0];
    const float* w1  = (const float*)d_in[1];
    const float* b1  = (const float*)d_in[2];
    const float* w2  = (const float*)d_in[3];
    const float* b2  = (const float*)d_in[4];
    const float* gam = (const float*)d_in[5];
    const float* bet = (const float*)d_in[6];
    const float* T   = (const float*)d_in[7];
    const float* lw  = (const float*)d_in[8];
    const float* lb  = (const float*)d_in[9];
    float* out = (float*)d_out;

    float* ws = (float*)d_ws;
    // Layout (float offsets), ws_size ~1GB (measured via harness fill):
    //   [0 .. 8,388,608)            h1 bf16 [4][64][4096][16] -> later Mpart bf16 [1024][8192]
    //   [8,388,608 .. 12,582,912)   h2b bf16 [64][131072]  (featb-layout, pre-BN)
    //   [12,582,912 .. +65,536)     Bw bf16
    //   then M (32000), ob (6400)
    //   then bnp (2048 doubles = 4096 slots), fpart (512 doubles = 1024 slots)
    __hip_bfloat16* h1 = (__hip_bfloat16*)ws;
    __hip_bfloat16* Mpart = (__hip_bfloat16*)ws;      // aliases h1 (dead after conv2)
    __hip_bfloat16* h2b = (__hip_bfloat16*)(ws + 8388608);
    __hip_bfloat16* Bw  = (__hip_bfloat16*)(ws + 12582912);
    float* M     = ws + 12582912 + 65536;
    float* ob    = M + 32000;
    double* bnp   = (double*)(ob + 6400);
    double* fpart = bnp + 2048;

    k_conv1p<<<1536, 256, 0, stream>>>(x, w1, b1, w2, h1, Bw);
    k_conv2<<<512, 256, 0, stream>>>(h1, Bw, b2, h2b);
    k_bnstats1<<<1024, 256, 0, stream>>>(h2b, bnp);
    k_mgemm<<<1024, 256, 0, stream>>>(h2b, bnp, gam, bet, T, Mpart);
    k_mreduce<<<125, 256, 0, stream>>>(Mpart, M);
    k_ob<<<100, 256, 0, stream>>>(M, ob);
    k_final1<<<512, 256, 0, stream>>>(h2b, bnp, gam, bet, lw, fpart);
    k_final2<<<1, 64, 0, stream>>>(fpart, ob, lw, lb, out);
}

// Round 12
// 167.798 us; speedup vs baseline: 13.3638x; 1.0656x over previous
//
#include <hip/hip_runtime.h>
#include <hip/hip_bf16.h>
#include <math.h>

#define BB 64
#define SS 128
#define C1 64
#define H1D 64
#define C2 128
#define H2D 32
#define FLAT 131072
#define NCOL 500
#define KCH 256      // split-K chunks in mgemm (deterministic partials, bf16)
#define KCSZ 512     // k per chunk  (KCH*KCSZ == FLAT)

typedef __attribute__((ext_vector_type(4))) float f32x4;
typedef __attribute__((ext_vector_type(8))) short bf16x8;

__device__ inline float bf2f(short s) {
    union { unsigned int u; float f; } z;
    z.u = ((unsigned int)(unsigned short)s) << 16;
    return z.f;
}

// ---------------- fused: prepw (blocks 0..511) + conv1 (blocks 512..1535) ----------------
__global__ __launch_bounds__(256) void k_conv1p(const float* __restrict__ x,
    const float* __restrict__ w, const float* __restrict__ bias,
    const float* __restrict__ w2,
    __hip_bfloat16* __restrict__ h1, __hip_bfloat16* __restrict__ Bw)
{
    int bid = blockIdx.x;
    if (bid < 512) {
      int i = bid*256 + threadIdx.x;             // 131072
      int jj = i & 7, oc = (i>>3)&127, kl8 = (i>>10)&31, stage = i>>15;
      int kl = kl8*8 + jj;
      int tap = kl >> 4, icl = kl & 15;
      int ic = stage*16 + icl;
      Bw[i] = __float2bfloat16(w2[(size_t)oc*1024 + ic*16 + tap]);
      return;
    }
    int tid = (bid - 512)*256 + threadIdx.x;     // (b, oh, ow)
    int ow = tid & 63, oh = (tid>>6)&63, bi = tid>>12;
    int ih0 = oh*2-1, iw0 = ow*2-1;
    float in[48];
    #pragma unroll
    for (int ic=0; ic<3; ic++)
      #pragma unroll
      for (int kh=0; kh<4; kh++)
        #pragma unroll
        for (int kw=0; kw<4; kw++) {
          int ih = ih0+kh, iw = iw0+kw;
          float v = 0.f;
          if ((unsigned)ih < 128u && (unsigned)iw < 128u)
            v = x[((size_t)(bi*3+ic)*SS + ih)*SS + iw];
          in[ic*16+kh*4+kw] = v;
        }
    #pragma unroll
    for (int g=0; g<4; g++) {
      __hip_bfloat16 outv[16];
      #pragma unroll
      for (int ocl=0; ocl<16; ocl++) {
        int oc = g*16 + ocl;
        float a = bias[oc];
        const float* wp = w + oc*48;             // wave-uniform -> scalar loads
        #pragma unroll
        for (int t=0; t<48; t++) a = fmaf(in[t], wp[t], a);
        a = a >= 0.f ? a : 0.2f*a;
        outv[ocl] = __float2bfloat16(a);
      }
      __hip_bfloat16* dst = h1 + (((size_t)g*BB + bi)*4096 + oh*64 + ow)*16;
      *(bf16x8*)(dst)     = *(bf16x8*)&outv[0];
      *(bf16x8*)(dst + 8) = *(bf16x8*)&outv[8];
    }
}

// ---------------- conv2 MFMA implicit GEMM -> h2b bf16; + per-block BN partials ----------------
// XCD pairing: nh = (bid>>3)&1 so the two nh-halves of one (bi,strip) share
// bid%8 -> same XCD -> second h1 staging pass hits L2.
__global__ __launch_bounds__(256) void k_conv2(const __hip_bfloat16* __restrict__ h1,
    const __hip_bfloat16* __restrict__ Bw, const float* __restrict__ b2,
    __hip_bfloat16* __restrict__ h2b, double* __restrict__ bnp2)
{
    int bid = blockIdx.x;
    int nh = (bid >> 3) & 1;
    int pair = (bid >> 4)*8 + (bid & 7);         // 0..255
    int bi = pair >> 2, strip = pair & 3;
    int lane = threadIdx.x & 63, wv = threadIdx.x >> 6;
    int l15 = lane & 15, kg = lane >> 4;

    __shared__ __align__(16) short tile[36*33*24];   // 57 KB
    __shared__ float2 bnl[4][16][16];                // 8 KB

    f32x4 acc[4][4];
    #pragma unroll
    for (int m=0;m<4;m++)
      #pragma unroll
      for (int n=0;n<4;n++) acc[m][n] = (f32x4)(0.f);

    int ihb = strip*16 - 1;

    for (int stage=0; stage<4; ++stage) {
      const __hip_bfloat16* hsrc = h1 + ((size_t)stage*BB + bi)*4096*16;
      for (int idx = threadIdx.x; idx < 2376; idx += 256) {
        int half = idx & 1, p = idx >> 1;        // p = ih_l*66 + iw_l
        int ih_l = p / 66, iw_l = p - ih_l*66;
        int ih = ihb + ih_l, iw = iw_l - 1;
        int row48 = (ih_l*2 + (iw_l&1))*33 + (iw_l>>1);
        bf16x8 v = (bf16x8)(0);
        if ((unsigned)ih < 64u && (unsigned)iw < 64u)
          v = *(const bf16x8*)(hsrc + ((size_t)(ih*64+iw)*16 + half*8));
        *(bf16x8*)&tile[row48*24 + half*8] = v;
      }
      __syncthreads();
      const __hip_bfloat16* bwst = Bw + (size_t)stage*32*128*8;
      #pragma unroll
      for (int j=0; j<8; j++) {
        bf16x8 bf[4];
        #pragma unroll
        for (int nf=0; nf<4; nf++)
          bf[nf] = *(const bf16x8*)(bwst + ((size_t)((j*4+kg)*128) + nh*64 + nf*16 + l15)*8);
        int tap = 2*j + (kg>>1);
        int kh = tap>>2, kw = tap&3;
        int icl0 = (kg&1)*8;
        bf16x8 af[4];
        #pragma unroll
        for (int mf=0; mf<4; mf++) {
          int oh_l = 2*wv + (mf>>1);
          int ow   = (mf&1)*16 + l15;
          int ih_l = 2*oh_l + kh;
          int iw_l = 2*ow + kw;
          int row48 = (ih_l*2 + (iw_l&1))*33 + (iw_l>>1);
          af[mf] = *(const bf16x8*)&tile[row48*24 + icl0];
        }
        #pragma unroll
        for (int mf=0; mf<4; mf++)
          #pragma unroll
          for (int nf=0; nf<4; nf++)
            acc[mf][nf] = __builtin_amdgcn_mfma_f32_16x16x32_bf16(af[mf], bf[nf], acc[mf][nf], 0, 0, 0);
      }
      __syncthreads();
    }
    // epilogue: write h2b + per-(block,oc) BN partials
    #pragma unroll
    for (int nf=0; nf<4; nf++) {
      int oc = nh*64 + nf*16 + l15;
      float bv = b2[oc];
      float s1 = 0.f, s2 = 0.f;
      #pragma unroll
      for (int mf=0; mf<4; mf++) {
        int p0 = wv*64 + mf*16 + kg*4;
        float v0 = acc[mf][nf][0] + bv;
        float v1 = acc[mf][nf][1] + bv;
        float v2 = acc[mf][nf][2] + bv;
        float v3 = acc[mf][nf][3] + bv;
        s1 += v0+v1+v2+v3;
        s2 = fmaf(v0,v0, fmaf(v1,v1, fmaf(v2,v2, fmaf(v3,v3, s2))));
        __hip_bfloat16 o4[4];
        o4[0] = __float2bfloat16(v0); o4[1] = __float2bfloat16(v1);
        o4[2] = __float2bfloat16(v2); o4[3] = __float2bfloat16(v3);
        *(double*)&h2b[((size_t)bi*C2 + oc)*1024 + strip*256 + p0] = *(double*)o4;
      }
      bnl[nf][wv*4+kg][l15] = make_float2(s1, s2);
    }
    __syncthreads();
    if (threadIdx.x < 64) {
      int nf = threadIdx.x >> 4, l = threadIdx.x & 15;
      double s1 = 0.0, s2 = 0.0;
      #pragma unroll
      for (int i=0;i<16;i++) {
        float2 v = bnl[nf][i][l];
        s1 += (double)v.x; s2 += (double)v.y;
      }
      int oc = nh*64 + nf*16 + l;                // 0..127
      // s1 bank: [0, 32768), s2 bank: [32768, 65536)
      // (R11 BUG: s2 base was 16384 -> overwrote s1 of oc>=64 -> negative var -> NaN)
      bnp2[(size_t)oc*256 + pair]         = s1;
      bnp2[32768 + (size_t)oc*256 + pair] = s2;
    }
}

// ---------------- BN reduce: 256 pair-partials -> stats[c]=scale, stats[128+c]=shift ----------------
__global__ __launch_bounds__(256) void k_bnred(const double* __restrict__ bnp2,
    const float* __restrict__ gamma, const float* __restrict__ beta,
    float* __restrict__ stats)
{
    int c = blockIdx.x;          // 0..127
    int p = threadIdx.x;         // 0..255
    double s1 = bnp2[(size_t)c*256 + p];
    double s2 = bnp2[32768 + (size_t)c*256 + p];
    __shared__ double r1[256], r2[256];
    r1[p] = s1; r2[p] = s2;
    __syncthreads();
    for (int st = 128; st > 0; st >>= 1) {
      if (p < st) { r1[p] += r1[p+st]; r2[p] += r2[p+st]; }
      __syncthreads();
    }
    if (p == 0) {
      double mean = r1[0] * (1.0/65536.0);
      double var  = r2[0] * (1.0/65536.0) - mean*mean;
      double rstd = 1.0 / sqrt(var + 1e-5);
      double sc = rstd * (double)gamma[c];
      stats[c]       = (float)sc;
      stats[C2 + c]  = (float)((double)beta[c] - mean*sc);
    }
}

// ---------------- M = BN(h2b) @ T via MFMA, LDS-staged T, BN inline ----------------
__global__ __launch_bounds__(256) void k_mgemm(const __hip_bfloat16* __restrict__ h2b,
    const float* __restrict__ stats, const float* __restrict__ T,
    __hip_bfloat16* __restrict__ Mpart)
{
    int t = threadIdx.x;
    int lane = t & 63, wv = t >> 6;
    int l15 = lane & 15, kg = lane >> 4;
    int bid = blockIdx.x;
    int xc = bid & 7, j = bid >> 3;
    int kc = xc*32 + (j >> 2);
    int ng = j & 3;
    int k0b = kc * KCSZ;

    int ch = kc >> 1;
    float sc = stats[ch], sh = stats[C2 + ch];

    __shared__ float Ts[2][32][134];   // 34.3 KB

    int f4c = t & 31, rbase = t >> 5;
    int cols4 = ng*128 + f4c*4;
    bool cvalid = cols4 < 500;

    f32x4 acc[4][2];
    #pragma unroll
    for (int m=0;m<4;m++) { acc[m][0] = (f32x4)(0.f); acc[m][1] = (f32x4)(0.f); }

    float4 tv0, tv1, tv2, tv3;
    {
      int ks0 = k0b;
      tv0 = cvalid ? *(const float4*)&T[(size_t)(ks0+rbase   )*NCOL + cols4] : make_float4(0,0,0,0);
      tv1 = cvalid ? *(const float4*)&T[(size_t)(ks0+rbase+ 8)*NCOL + cols4] : make_float4(0,0,0,0);
      tv2 = cvalid ? *(const float4*)&T[(size_t)(ks0+rbase+16)*NCOL + cols4] : make_float4(0,0,0,0);
      tv3 = cvalid ? *(const float4*)&T[(size_t)(ks0+rbase+24)*NCOL + cols4] : make_float4(0,0,0,0);
      float* d0 = &Ts[0][rbase   ][f4c*4];
      float* d1 = &Ts[0][rbase+ 8][f4c*4];
      float* d2 = &Ts[0][rbase+16][f4c*4];
      float* d3 = &Ts[0][rbase+24][f4c*4];
      *(float2*)d0 = make_float2(tv0.x,tv0.y); *(float2*)(d0+2) = make_float2(tv0.z,tv0.w);
      *(float2*)d1 = make_float2(tv1.x,tv1.y); *(float2*)(d1+2) = make_float2(tv1.z,tv1.w);
      *(float2*)d2 = make_float2(tv2.x,tv2.y); *(float2*)(d2+2) = make_float2(tv2.z,tv2.w);
      *(float2*)d3 = make_float2(tv3.x,tv3.y); *(float2*)(d3+2) = make_float2(tv3.z,tv3.w);
    }
    __syncthreads();

    for (int s = 0; s < 16; s++) {
      int cur = s & 1;
      if (s < 15) {
        int ks0 = k0b + (s+1)*32;
        tv0 = cvalid ? *(const float4*)&T[(size_t)(ks0+rbase   )*NCOL + cols4] : make_float4(0,0,0,0);
        tv1 = cvalid ? *(const float4*)&T[(size_t)(ks0+rbase+ 8)*NCOL + cols4] : make_float4(0,0,0,0);
        tv2 = cvalid ? *(const float4*)&T[(size_t)(ks0+rbase+16)*NCOL + cols4] : make_float4(0,0,0,0);
        tv3 = cvalid ? *(const float4*)&T[(size_t)(ks0+rbase+24)*NCOL + cols4] : make_float4(0,0,0,0);
      }
      {
        int k0 = k0b + s*32;
        bf16x8 af[4];
        #pragma unroll
        for (int mf=0; mf<4; mf++) {
          bf16x8 raw = *(const bf16x8*)(h2b + (size_t)(mf*16 + l15)*FLAT + k0 + kg*8);
          __hip_bfloat16 ta[8];
          #pragma unroll
          for (int jj=0; jj<8; jj++) {
            float f = fmaf(bf2f(raw[jj]), sc, sh);
            f = f >= 0.f ? f : 0.2f*f;
            ta[jj] = __float2bfloat16(f);
          }
          af[mf] = *(bf16x8*)ta;
        }
        bf16x8 bfr[2];
        #pragma unroll
        for (int nf=0; nf<2; nf++) {
          int c = wv*32 + nf*16 + l15;
          __hip_bfloat16 tb[8];
          #pragma unroll
          for (int jj=0; jj<8; jj++)
            tb[jj] = __float2bfloat16(Ts[cur][kg*8+jj][c]);
          bfr[nf] = *(bf16x8*)tb;
        }
        #pragma unroll
        for (int mf=0;mf<4;mf++)
          #pragma unroll
          for (int nf=0;nf<2;nf++)
            acc[mf][nf] = __builtin_amdgcn_mfma_f32_16x16x32_bf16(af[mf], bfr[nf], acc[mf][nf], 0, 0, 0);
      }
      __syncthreads();
      if (s < 15) {
        int nb = cur ^ 1;
        float* d0 = &Ts[nb][rbase   ][f4c*4];
        float* d1 = &Ts[nb][rbase+ 8][f4c*4];
        float* d2 = &Ts[nb][rbase+16][f4c*4];
        float* d3 = &Ts[nb][rbase+24][f4c*4];
        *(float2*)d0 = make_float2(tv0.x,tv0.y); *(float2*)(d0+2) = make_float2(tv0.z,tv0.w);
        *(float2*)d1 = make_float2(tv1.x,tv1.y); *(float2*)(d1+2) = make_float2(tv1.z,tv1.w);
        *(float2*)d2 = make_float2(tv2.x,tv2.y); *(float2*)(d2+2) = make_float2(tv2.z,tv2.w);
        *(float2*)d3 = make_float2(tv3.x,tv3.y); *(float2*)(d3+2) = make_float2(tv3.z,tv3.w);
        __syncthreads();
      }
    }
    __hip_bfloat16* op = Mpart + (size_t)(kc*4 + ng)*8192;
    #pragma unroll
    for (int mf=0; mf<4; mf++) {
      __hip_bfloat16 buf[8];
      #pragma unroll
      for (int nf=0; nf<2; nf++)
        #pragma unroll
        for (int q=0; q<4; q++)
          buf[nf*4+q] = __float2bfloat16(acc[mf][nf][q]);
      *(bf16x8*)(op + ((size_t)mf*256 + t)*8) = *(bf16x8*)buf;
    }
}

// ---------------- mreduce stage A: coalesced 8-chunk partial sums -> Mpart2 fp32 ----------------
__global__ __launch_bounds__(256) void k_mreduceA(const __hip_bfloat16* __restrict__ Mpart,
    float* __restrict__ Mpart2)
{
    int ng = blockIdx.x & 3, kg8 = blockIdx.x >> 2;
    int t = threadIdx.x;
    f32x4 a0[4], a1[4];
    #pragma unroll
    for (int mf=0; mf<4; mf++) { a0[mf] = (f32x4)(0.f); a1[mf] = (f32x4)(0.f); }
    #pragma unroll
    for (int kcl=0; kcl<8; kcl++) {
      int kc = kg8*8 + kcl;
      const __hip_bfloat16* ch = Mpart + (size_t)(kc*4 + ng)*8192;
      #pragma unroll
      for (int mf=0; mf<4; mf++) {
        bf16x8 v = *(const bf16x8*)(ch + ((size_t)mf*256 + t)*8);
        a0[mf][0] += bf2f(v[0]); a0[mf][1] += bf2f(v[1]);
        a0[mf][2] += bf2f(v[2]); a0[mf][3] += bf2f(v[3]);
        a1[mf][0] += bf2f(v[4]); a1[mf][1] += bf2f(v[5]);
        a1[mf][2] += bf2f(v[6]); a1[mf][3] += bf2f(v[7]);
      }
    }
    #pragma unroll
    for (int mf=0; mf<4; mf++) {
      float* dst = Mpart2 + ((size_t)(ng*32 + kg8)*4 + mf)*2048 + t*8;
      *(f32x4*)dst = a0[mf];
      *(f32x4*)(dst+4) = a1[mf];
    }
}

// ---------------- minibatch discrimination: o_b (sums stage-A partials directly) ----------------
__global__ __launch_bounds__(256) void k_ob(const float* __restrict__ Mpart2,
    float* __restrict__ ob)
{
    int o = blockIdx.x;   // 0..99
    __shared__ float Ms[320];
    __shared__ float red[256];
    for (int idx = threadIdx.x; idx < 320; idx += 256) {
      int a = idx / 5, d = idx - a*5;
      int r = a, c = o*5 + d;
      int mf = r >> 4, kg = (r >> 2) & 3, q = r & 3;
      int ng = c >> 7, wv = (c >> 5) & 3, nf = (c >> 4) & 1, l15 = c & 15;
      int t = wv*64 + kg*16 + l15, j8 = nf*4 + q;
      const float* p = Mpart2 + ((size_t)(ng*32)*4 + mf)*2048 + t*8 + j8;
      float s = 0.f;
      #pragma unroll 8
      for (int kg8 = 0; kg8 < 32; kg8++) s += p[(size_t)kg8*8192];
      Ms[idx] = s;
    }
    __syncthreads();
    int b = threadIdx.x & 63, aq = threadIdx.x >> 6;
    float s = 0.f;
    for (int a = aq*16; a < aq*16+16; a++) {
      float n = 0.f;
      #pragma unroll
      for (int d=0; d<5; d++) n += fabsf(Ms[a*5+d] - Ms[b*5+d]);
      s += expf(-n);
    }
    red[threadIdx.x] = s;
    __syncthreads();
    if (threadIdx.x < 64)
      ob[(size_t)b*100 + o] = red[b] + red[64+b] + red[128+b] + red[192+b];
}

// ---------------- final linear stage1: BN inline from bf16 h2b, fp64 partial dots ----------------
__global__ __launch_bounds__(256) void k_final1(const __hip_bfloat16* __restrict__ h2b,
    const float* __restrict__ stats, const float* __restrict__ lw,
    double* __restrict__ fpart)
{
    int bx = blockIdx.x;          // 512 = b*8 + s
    int b = bx >> 3, s = bx & 7;
    __shared__ float scs[16], shs[16];
    if (threadIdx.x < 16) {
      scs[threadIdx.x] = stats[s*16 + threadIdx.x];
      shs[threadIdx.x] = stats[C2 + s*16 + threadIdx.x];
    }
    __syncthreads();
    const __hip_bfloat16* hp = h2b + (size_t)b*FLAT;
    double acc = 0.0;
    for (int g = s*2048 + threadIdx.x; g < (s+1)*2048; g += 256) {  // bf16x8 groups
      int k = g*8;
      int cl = (k >> 10) & 15;
      float sc = scs[cl], sh = shs[cl];
      bf16x8 v = *(const bf16x8*)&hp[k];
      float4 w0 = *(const float4*)&lw[k];
      float4 w1 = *(const float4*)&lw[k+4];
      float f0 = fmaf(bf2f(v[0]), sc, sh); f0 = f0>=0.f?f0:0.2f*f0;
      float f1 = fmaf(bf2f(v[1]), sc, sh); f1 = f1>=0.f?f1:0.2f*f1;
      float f2 = fmaf(bf2f(v[2]), sc, sh); f2 = f2>=0.f?f2:0.2f*f2;
      float f3 = fmaf(bf2f(v[3]), sc, sh); f3 = f3>=0.f?f3:0.2f*f3;
      float f4 = fmaf(bf2f(v[4]), sc, sh); f4 = f4>=0.f?f4:0.2f*f4;
      float f5 = fmaf(bf2f(v[5]), sc, sh); f5 = f5>=0.f?f5:0.2f*f5;
      float f6 = fmaf(bf2f(v[6]), sc, sh); f6 = f6>=0.f?f6:0.2f*f6;
      float f7 = fmaf(bf2f(v[7]), sc, sh); f7 = f7>=0.f?f7:0.2f*f7;
      acc = fma((double)f0, (double)w0.x, acc);
      acc = fma((double)f1, (double)w0.y, acc);
      acc = fma((double)f2, (double)w0.z, acc);
      acc = fma((double)f3, (double)w0.w, acc);
      acc = fma((double)f4, (double)w1.x, acc);
      acc = fma((double)f5, (double)w1.y, acc);
      acc = fma((double)f6, (double)w1.z, acc);
      acc = fma((double)f7, (double)w1.w, acc);
    }
    __shared__ double red[256];
    red[threadIdx.x] = acc;
    __syncthreads();
    for (int st = 128; st > 0; st >>= 1) {
      if (threadIdx.x < st) red[threadIdx.x] += red[threadIdx.x + st];
      __syncthreads();
    }
    if (threadIdx.x == 0) fpart[bx] = red[0];
}

__global__ void k_final2(const double* __restrict__ fpart,
    const float* __restrict__ ob, const float* __restrict__ lw,
    const float* __restrict__ lb, float* __restrict__ out)
{
    int b = threadIdx.x;   // 64 threads, 1 block
    double s = 0.0;
    #pragma unroll
    for (int i = 0; i < 8; i++) s += fpart[b*8 + i];
    for (int o = 0; o < 100; o++)
      s = fma((double)ob[(size_t)b*100 + o], (double)lw[FLAT + o], s);
    s += (double)lb[0];
    out[b] = (float)(1.0 / (1.0 + exp(-s)));
}

extern "C" void kernel_launch(void* const* d_in, const int* in_sizes, int n_in,
                              void* d_out, int out_size, void* d_ws, size_t ws_size,
                              hipStream_t stream)
{
    const float* x   = (const float*)d_in[0];
    const float* w1  = (const float*)d_in[1];
    const float* b1  = (const float*)d_in[2];
    const float* w2  = (const float*)d_in[3];
    const float* b2  = (const float*)d_in[4];
    const float* gam = (const float*)d_in[5];
    const float* bet = (const float*)d_in[6];
    const float* T   = (const float*)d_in[7];
    const float* lw  = (const float*)d_in[8];
    const float* lb  = (const float*)d_in[9];
    float* out = (float*)d_out;

    float* ws = (float*)d_ws;
    // Layout (float offsets), ws ~1GB:
    //   [0 .. 8,388,608)            h1 bf16 -> later Mpart bf16 [1024][8192]
    //   [8,388,608 .. 12,582,912)   h2b bf16 [64][131072]
    //   [12,582,912 .. 12,648,448)  Bw bf16
    //   [12,648,448 .. 12,648,704)  stats (256 f32)
    //   [12,648,704 .. 12,655,104)  ob (6400 f32)
    //   [12,655,104 .. 13,703,680)  Mpart2 (1,048,576 f32)
    //   [13,703,680 .. 13,834,752)  bnp2 (65,536 doubles: s1 [0,32768), s2 [32768,65536))
    //   [13,834,752 .. +1024)       fpart (512 doubles)
    __hip_bfloat16* h1 = (__hip_bfloat16*)ws;
    __hip_bfloat16* Mpart = (__hip_bfloat16*)ws;      // aliases h1 (dead after conv2)
    __hip_bfloat16* h2b = (__hip_bfloat16*)(ws + 8388608);
    __hip_bfloat16* Bw  = (__hip_bfloat16*)(ws + 12582912);
    float* stats = ws + 12648448;
    float* ob    = ws + 12648704;
    float* Mpart2 = ws + 12655104;
    double* bnp2  = (double*)(ws + 13703680);
    double* fpart = (double*)(ws + 13834752);

    k_conv1p<<<1536, 256, 0, stream>>>(x, w1, b1, w2, h1, Bw);
    k_conv2<<<512, 256, 0, stream>>>(h1, Bw, b2, h2b, bnp2);
    k_bnred<<<128, 256, 0, stream>>>(bnp2, gam, bet, stats);
    k_mgemm<<<1024, 256, 0, stream>>>(h2b, stats, T, Mpart);
    k_mreduceA<<<128, 256, 0, stream>>>(Mpart, Mpart2);
    k_ob<<<100, 256, 0, stream>>>(Mpart2, ob);
    k_final1<<<512, 256, 0, stream>>>(h2b, stats, lw, fpart);
    k_final2<<<1, 64, 0, stream>>>(fpart, ob, lw, lb, out);
}

// Round 13
// 164.308 us; speedup vs baseline: 13.6478x; 1.0212x over previous
//
#include <hip/hip_runtime.h>
#include <hip/hip_bf16.h>
#include <math.h>

#define BB 64
#define SS 128
#define C1 64
#define H1D 64
#define C2 128
#define H2D 32
#define FLAT 131072
#define NCOL 500
#define KCH 256      // split-K chunks in mgemm (deterministic partials, bf16)
#define KCSZ 512     // k per chunk  (KCH*KCSZ == FLAT)

typedef __attribute__((ext_vector_type(4))) float f32x4;
typedef __attribute__((ext_vector_type(8))) short bf16x8;

__device__ inline float bf2f(short s) {
    union { unsigned int u; float f; } z;
    z.u = ((unsigned int)(unsigned short)s) << 16;
    return z.f;
}

// ---------------- fused: prepw (blocks 0..511) + conv1 (blocks 512..1535) ----------------
__global__ __launch_bounds__(256) void k_conv1p(const float* __restrict__ x,
    const float* __restrict__ w, const float* __restrict__ bias,
    const float* __restrict__ w2,
    __hip_bfloat16* __restrict__ h1, __hip_bfloat16* __restrict__ Bw)
{
    int bid = blockIdx.x;
    if (bid < 512) {
      int i = bid*256 + threadIdx.x;             // 131072
      int jj = i & 7, oc = (i>>3)&127, kl8 = (i>>10)&31, stage = i>>15;
      int kl = kl8*8 + jj;
      int tap = kl >> 4, icl = kl & 15;
      int ic = stage*16 + icl;
      Bw[i] = __float2bfloat16(w2[(size_t)oc*1024 + ic*16 + tap]);
      return;
    }
    int tid = (bid - 512)*256 + threadIdx.x;     // (b, oh, ow)
    int ow = tid & 63, oh = (tid>>6)&63, bi = tid>>12;
    int ih0 = oh*2-1, iw0 = ow*2-1;
    float in[48];
    #pragma unroll
    for (int ic=0; ic<3; ic++)
      #pragma unroll
      for (int kh=0; kh<4; kh++)
        #pragma unroll
        for (int kw=0; kw<4; kw++) {
          int ih = ih0+kh, iw = iw0+kw;
          float v = 0.f;
          if ((unsigned)ih < 128u && (unsigned)iw < 128u)
            v = x[((size_t)(bi*3+ic)*SS + ih)*SS + iw];
          in[ic*16+kh*4+kw] = v;
        }
    #pragma unroll
    for (int g=0; g<4; g++) {
      __hip_bfloat16 outv[16];
      #pragma unroll
      for (int ocl=0; ocl<16; ocl++) {
        int oc = g*16 + ocl;
        float a = bias[oc];
        const float* wp = w + oc*48;             // wave-uniform -> scalar loads
        #pragma unroll
        for (int t=0; t<48; t++) a = fmaf(in[t], wp[t], a);
        a = a >= 0.f ? a : 0.2f*a;
        outv[ocl] = __float2bfloat16(a);
      }
      __hip_bfloat16* dst = h1 + (((size_t)g*BB + bi)*4096 + oh*64 + ow)*16;
      *(bf16x8*)(dst)     = *(bf16x8*)&outv[0];
      *(bf16x8*)(dst + 8) = *(bf16x8*)&outv[8];
    }
}

// ---------------- conv2 MFMA implicit GEMM -> h2b bf16; + per-block BN partials ----------------
__global__ __launch_bounds__(256) void k_conv2(const __hip_bfloat16* __restrict__ h1,
    const __hip_bfloat16* __restrict__ Bw, const float* __restrict__ b2,
    __hip_bfloat16* __restrict__ h2b, double* __restrict__ bnp2)
{
    int bid = blockIdx.x;
    int nh = (bid >> 3) & 1;
    int pair = (bid >> 4)*8 + (bid & 7);         // 0..255
    int bi = pair >> 2, strip = pair & 3;
    int lane = threadIdx.x & 63, wv = threadIdx.x >> 6;
    int l15 = lane & 15, kg = lane >> 4;

    __shared__ __align__(16) short tile[36*33*24];   // 57 KB
    __shared__ float2 bnl[4][16][16];                // 8 KB

    f32x4 acc[4][4];
    #pragma unroll
    for (int m=0;m<4;m++)
      #pragma unroll
      for (int n=0;n<4;n++) acc[m][n] = (f32x4)(0.f);

    int ihb = strip*16 - 1;

    for (int stage=0; stage<4; ++stage) {
      const __hip_bfloat16* hsrc = h1 + ((size_t)stage*BB + bi)*4096*16;
      for (int idx = threadIdx.x; idx < 2376; idx += 256) {
        int half = idx & 1, p = idx >> 1;        // p = ih_l*66 + iw_l
        int ih_l = p / 66, iw_l = p - ih_l*66;
        int ih = ihb + ih_l, iw = iw_l - 1;
        int row48 = (ih_l*2 + (iw_l&1))*33 + (iw_l>>1);
        bf16x8 v = (bf16x8)(0);
        if ((unsigned)ih < 64u && (unsigned)iw < 64u)
          v = *(const bf16x8*)(hsrc + ((size_t)(ih*64+iw)*16 + half*8));
        *(bf16x8*)&tile[row48*24 + half*8] = v;
      }
      __syncthreads();
      const __hip_bfloat16* bwst = Bw + (size_t)stage*32*128*8;
      #pragma unroll
      for (int j=0; j<8; j++) {
        bf16x8 bf[4];
        #pragma unroll
        for (int nf=0; nf<4; nf++)
          bf[nf] = *(const bf16x8*)(bwst + ((size_t)((j*4+kg)*128) + nh*64 + nf*16 + l15)*8);
        int tap = 2*j + (kg>>1);
        int kh = tap>>2, kw = tap&3;
        int icl0 = (kg&1)*8;
        bf16x8 af[4];
        #pragma unroll
        for (int mf=0; mf<4; mf++) {
          int oh_l = 2*wv + (mf>>1);
          int ow   = (mf&1)*16 + l15;
          int ih_l = 2*oh_l + kh;
          int iw_l = 2*ow + kw;
          int row48 = (ih_l*2 + (iw_l&1))*33 + (iw_l>>1);
          af[mf] = *(const bf16x8*)&tile[row48*24 + icl0];
        }
        #pragma unroll
        for (int mf=0; mf<4; mf++)
          #pragma unroll
          for (int nf=0; nf<4; nf++)
            acc[mf][nf] = __builtin_amdgcn_mfma_f32_16x16x32_bf16(af[mf], bf[nf], acc[mf][nf], 0, 0, 0);
      }
      __syncthreads();
    }
    #pragma unroll
    for (int nf=0; nf<4; nf++) {
      int oc = nh*64 + nf*16 + l15;
      float bv = b2[oc];
      float s1 = 0.f, s2 = 0.f;
      #pragma unroll
      for (int mf=0; mf<4; mf++) {
        int p0 = wv*64 + mf*16 + kg*4;
        float v0 = acc[mf][nf][0] + bv;
        float v1 = acc[mf][nf][1] + bv;
        float v2 = acc[mf][nf][2] + bv;
        float v3 = acc[mf][nf][3] + bv;
        s1 += v0+v1+v2+v3;
        s2 = fmaf(v0,v0, fmaf(v1,v1, fmaf(v2,v2, fmaf(v3,v3, s2))));
        __hip_bfloat16 o4[4];
        o4[0] = __float2bfloat16(v0); o4[1] = __float2bfloat16(v1);
        o4[2] = __float2bfloat16(v2); o4[3] = __float2bfloat16(v3);
        *(double*)&h2b[((size_t)bi*C2 + oc)*1024 + strip*256 + p0] = *(double*)o4;
      }
      bnl[nf][wv*4+kg][l15] = make_float2(s1, s2);
    }
    __syncthreads();
    if (threadIdx.x < 64) {
      int nf = threadIdx.x >> 4, l = threadIdx.x & 15;
      double s1 = 0.0, s2 = 0.0;
      #pragma unroll
      for (int i=0;i<16;i++) {
        float2 v = bnl[nf][i][l];
        s1 += (double)v.x; s2 += (double)v.y;
      }
      int oc = nh*64 + nf*16 + l;                // 0..127
      bnp2[(size_t)oc*256 + pair]         = s1;  // s1 bank [0,32768)
      bnp2[32768 + (size_t)oc*256 + pair] = s2;  // s2 bank [32768,65536)
    }
}

// ---------------- fused: mgemm (blocks 0..1023) + final1 (blocks 1024..1535) ----------------
// Both consume {h2b, bnp2}; BN stats computed inline per block (replaces k_bnred).
__global__ __launch_bounds__(256) void k_mgf(const __hip_bfloat16* __restrict__ h2b,
    const double* __restrict__ bnp2, const float* __restrict__ gamma,
    const float* __restrict__ beta, const float* __restrict__ T,
    const float* __restrict__ lw,
    __hip_bfloat16* __restrict__ Mpart, double* __restrict__ fpart)
{
    __shared__ __align__(16) char smem[38432];
    int t = threadIdx.x;
    int bid = blockIdx.x;

    if (bid < 1024) {
      // ================= mgemm path =================
      int lane = t & 63, wv = t >> 6;
      int l15 = lane & 15, kg = lane >> 4;
      int xc = bid & 7, j = bid >> 3;
      int kc = xc*32 + (j >> 2);
      int ng = j & 3;
      int k0b = kc * KCSZ;
      int ch = kc >> 1;

      // inline BN stats for channel ch (LDS region beyond Ts)
      double* r1 = (double*)(smem + 34304);
      double* r2 = (double*)(smem + 34304 + 2048);
      float*  stf = (float*)(smem + 34304 + 4096);
      r1[t] = bnp2[(size_t)ch*256 + t];
      r2[t] = bnp2[32768 + (size_t)ch*256 + t];
      __syncthreads();
      for (int st = 128; st > 0; st >>= 1) {
        if (t < st) { r1[t] += r1[t+st]; r2[t] += r2[t+st]; }
        __syncthreads();
      }
      if (t == 0) {
        double mean = r1[0] * (1.0/65536.0);
        double var  = r2[0] * (1.0/65536.0) - mean*mean;
        double rstd = 1.0 / sqrt(var + 1e-5);
        double scd  = rstd * (double)gamma[ch];
        stf[0] = (float)scd;
        stf[1] = (float)((double)beta[ch] - mean*scd);
      }
      __syncthreads();
      float sc = stf[0], sh = stf[1];

      typedef float TsRow[134];
      TsRow* Ts0 = (TsRow*)smem;          // Ts[2][32][134] overlay
      TsRow* Ts1 = (TsRow*)(smem + 32*134*4);

      int f4c = t & 31, rbase = t >> 5;
      int cols4 = ng*128 + f4c*4;
      bool cvalid = cols4 < 500;

      f32x4 acc[4][2];
      #pragma unroll
      for (int m=0;m<4;m++) { acc[m][0] = (f32x4)(0.f); acc[m][1] = (f32x4)(0.f); }

      float4 tv0, tv1, tv2, tv3;
      {
        int ks0 = k0b;
        tv0 = cvalid ? *(const float4*)&T[(size_t)(ks0+rbase   )*NCOL + cols4] : make_float4(0,0,0,0);
        tv1 = cvalid ? *(const float4*)&T[(size_t)(ks0+rbase+ 8)*NCOL + cols4] : make_float4(0,0,0,0);
        tv2 = cvalid ? *(const float4*)&T[(size_t)(ks0+rbase+16)*NCOL + cols4] : make_float4(0,0,0,0);
        tv3 = cvalid ? *(const float4*)&T[(size_t)(ks0+rbase+24)*NCOL + cols4] : make_float4(0,0,0,0);
        float* d0 = &Ts0[rbase   ][f4c*4];
        float* d1 = &Ts0[rbase+ 8][f4c*4];
        float* d2 = &Ts0[rbase+16][f4c*4];
        float* d3 = &Ts0[rbase+24][f4c*4];
        *(float2*)d0 = make_float2(tv0.x,tv0.y); *(float2*)(d0+2) = make_float2(tv0.z,tv0.w);
        *(float2*)d1 = make_float2(tv1.x,tv1.y); *(float2*)(d1+2) = make_float2(tv1.z,tv1.w);
        *(float2*)d2 = make_float2(tv2.x,tv2.y); *(float2*)(d2+2) = make_float2(tv2.z,tv2.w);
        *(float2*)d3 = make_float2(tv3.x,tv3.y); *(float2*)(d3+2) = make_float2(tv3.z,tv3.w);
      }
      __syncthreads();

      for (int s = 0; s < 16; s++) {
        TsRow* Tc = (s & 1) ? Ts1 : Ts0;
        TsRow* Tn = (s & 1) ? Ts0 : Ts1;
        if (s < 15) {
          int ks0 = k0b + (s+1)*32;
          tv0 = cvalid ? *(const float4*)&T[(size_t)(ks0+rbase   )*NCOL + cols4] : make_float4(0,0,0,0);
          tv1 = cvalid ? *(const float4*)&T[(size_t)(ks0+rbase+ 8)*NCOL + cols4] : make_float4(0,0,0,0);
          tv2 = cvalid ? *(const float4*)&T[(size_t)(ks0+rbase+16)*NCOL + cols4] : make_float4(0,0,0,0);
          tv3 = cvalid ? *(const float4*)&T[(size_t)(ks0+rbase+24)*NCOL + cols4] : make_float4(0,0,0,0);
        }
        {
          int k0 = k0b + s*32;
          bf16x8 af[4];
          #pragma unroll
          for (int mf=0; mf<4; mf++) {
            bf16x8 raw = *(const bf16x8*)(h2b + (size_t)(mf*16 + l15)*FLAT + k0 + kg*8);
            __hip_bfloat16 ta[8];
            #pragma unroll
            for (int jj=0; jj<8; jj++) {
              float f = fmaf(bf2f(raw[jj]), sc, sh);
              f = f >= 0.f ? f : 0.2f*f;
              ta[jj] = __float2bfloat16(f);
            }
            af[mf] = *(bf16x8*)ta;
          }
          bf16x8 bfr[2];
          #pragma unroll
          for (int nf=0; nf<2; nf++) {
            int c = wv*32 + nf*16 + l15;
            __hip_bfloat16 tb[8];
            #pragma unroll
            for (int jj=0; jj<8; jj++)
              tb[jj] = __float2bfloat16(Tc[kg*8+jj][c]);
            bfr[nf] = *(bf16x8*)tb;
          }
          #pragma unroll
          for (int mf=0;mf<4;mf++)
            #pragma unroll
            for (int nf=0;nf<2;nf++)
              acc[mf][nf] = __builtin_amdgcn_mfma_f32_16x16x32_bf16(af[mf], bfr[nf], acc[mf][nf], 0, 0, 0);
        }
        __syncthreads();
        if (s < 15) {
          float* d0 = &Tn[rbase   ][f4c*4];
          float* d1 = &Tn[rbase+ 8][f4c*4];
          float* d2 = &Tn[rbase+16][f4c*4];
          float* d3 = &Tn[rbase+24][f4c*4];
          *(float2*)d0 = make_float2(tv0.x,tv0.y); *(float2*)(d0+2) = make_float2(tv0.z,tv0.w);
          *(float2*)d1 = make_float2(tv1.x,tv1.y); *(float2*)(d1+2) = make_float2(tv1.z,tv1.w);
          *(float2*)d2 = make_float2(tv2.x,tv2.y); *(float2*)(d2+2) = make_float2(tv2.z,tv2.w);
          *(float2*)d3 = make_float2(tv3.x,tv3.y); *(float2*)(d3+2) = make_float2(tv3.z,tv3.w);
          __syncthreads();
        }
      }
      __hip_bfloat16* op = Mpart + (size_t)(kc*4 + ng)*8192;
      #pragma unroll
      for (int mf=0; mf<4; mf++) {
        __hip_bfloat16 buf[8];
        #pragma unroll
        for (int nf=0; nf<2; nf++)
          #pragma unroll
          for (int q=0; q<4; q++)
            buf[nf*4+q] = __float2bfloat16(acc[mf][nf][q]);
        *(bf16x8*)(op + ((size_t)mf*256 + t)*8) = *(bf16x8*)buf;
      }
      return;
    }

    // ================= final1 path =================
    int bx = bid - 1024;          // 0..511 = b*8 + s
    int b = bx >> 3, s = bx & 7;
    // inline BN stats for channels s*16 .. s*16+15
    double* rA = (double*)smem;                 // [16][16] s1 partials
    double* rB = (double*)(smem + 2048);        // [16][16] s2 partials
    float*  scs = (float*)(smem + 4096);        // 16 floats
    float*  shs = (float*)(smem + 4096 + 64);   // 16 floats
    double* red = (double*)(smem + 8192);       // 256 doubles
    {
      int cl = t >> 4, i = t & 15;
      int c = s*16 + cl;
      double a1 = 0.0, a2 = 0.0;
      #pragma unroll
      for (int q=0;q<16;q++) {
        a1 += bnp2[(size_t)c*256 + i*16 + q];
        a2 += bnp2[32768 + (size_t)c*256 + i*16 + q];
      }
      rA[cl*16+i] = a1; rB[cl*16+i] = a2;
      __syncthreads();
      for (int st = 8; st > 0; st >>= 1) {
        if (i < st) { rA[cl*16+i] += rA[cl*16+i+st]; rB[cl*16+i] += rB[cl*16+i+st]; }
        __syncthreads();
      }
      if (i == 0) {
        double mean = rA[cl*16] * (1.0/65536.0);
        double var  = rB[cl*16] * (1.0/65536.0) - mean*mean;
        double rstd = 1.0 / sqrt(var + 1e-5);
        double scd  = rstd * (double)gamma[c];
        scs[cl] = (float)scd;
        shs[cl] = (float)((double)beta[c] - mean*scd);
      }
      __syncthreads();
    }
    const __hip_bfloat16* hp = h2b + (size_t)b*FLAT;
    double acc = 0.0;
    for (int g = s*2048 + t; g < (s+1)*2048; g += 256) {  // bf16x8 groups
      int k = g*8;
      int cl = (k >> 10) & 15;
      float sc = scs[cl], sh = shs[cl];
      bf16x8 v = *(const bf16x8*)&hp[k];
      float4 w0 = *(const float4*)&lw[k];
      float4 w1 = *(const float4*)&lw[k+4];
      float f0 = fmaf(bf2f(v[0]), sc, sh); f0 = f0>=0.f?f0:0.2f*f0;
      float f1 = fmaf(bf2f(v[1]), sc, sh); f1 = f1>=0.f?f1:0.2f*f1;
      float f2 = fmaf(bf2f(v[2]), sc, sh); f2 = f2>=0.f?f2:0.2f*f2;
      float f3 = fmaf(bf2f(v[3]), sc, sh); f3 = f3>=0.f?f3:0.2f*f3;
      float f4 = fmaf(bf2f(v[4]), sc, sh); f4 = f4>=0.f?f4:0.2f*f4;
      float f5 = fmaf(bf2f(v[5]), sc, sh); f5 = f5>=0.f?f5:0.2f*f5;
      float f6 = fmaf(bf2f(v[6]), sc, sh); f6 = f6>=0.f?f6:0.2f*f6;
      float f7 = fmaf(bf2f(v[7]), sc, sh); f7 = f7>=0.f?f7:0.2f*f7;
      acc = fma((double)f0, (double)w0.x, acc);
      acc = fma((double)f1, (double)w0.y, acc);
      acc = fma((double)f2, (double)w0.z, acc);
      acc = fma((double)f3, (double)w0.w, acc);
      acc = fma((double)f4, (double)w1.x, acc);
      acc = fma((double)f5, (double)w1.y, acc);
      acc = fma((double)f6, (double)w1.z, acc);
      acc = fma((double)f7, (double)w1.w, acc);
    }
    red[t] = acc;
    __syncthreads();
    for (int st = 128; st > 0; st >>= 1) {
      if (t < st) red[t] += red[t + st];
      __syncthreads();
    }
    if (t == 0) fpart[bx] = red[0];
}

// ---------------- mreduce stage A: coalesced 8-chunk partial sums -> Mpart2 fp32 ----------------
__global__ __launch_bounds__(256) void k_mreduceA(const __hip_bfloat16* __restrict__ Mpart,
    float* __restrict__ Mpart2)
{
    int ng = blockIdx.x & 3, kg8 = blockIdx.x >> 2;
    int t = threadIdx.x;
    f32x4 a0[4], a1[4];
    #pragma unroll
    for (int mf=0; mf<4; mf++) { a0[mf] = (f32x4)(0.f); a1[mf] = (f32x4)(0.f); }
    #pragma unroll
    for (int kcl=0; kcl<8; kcl++) {
      int kc = kg8*8 + kcl;
      const __hip_bfloat16* ch = Mpart + (size_t)(kc*4 + ng)*8192;
      #pragma unroll
      for (int mf=0; mf<4; mf++) {
        bf16x8 v = *(const bf16x8*)(ch + ((size_t)mf*256 + t)*8);
        a0[mf][0] += bf2f(v[0]); a0[mf][1] += bf2f(v[1]);
        a0[mf][2] += bf2f(v[2]); a0[mf][3] += bf2f(v[3]);
        a1[mf][0] += bf2f(v[4]); a1[mf][1] += bf2f(v[5]);
        a1[mf][2] += bf2f(v[6]); a1[mf][3] += bf2f(v[7]);
      }
    }
    #pragma unroll
    for (int mf=0; mf<4; mf++) {
      float* dst = Mpart2 + ((size_t)(ng*32 + kg8)*4 + mf)*2048 + t*8;
      *(f32x4*)dst = a0[mf];
      *(f32x4*)(dst+4) = a1[mf];
    }
}

// ---------------- minibatch discrimination: o_b ----------------
__global__ __launch_bounds__(256) void k_ob(const float* __restrict__ Mpart2,
    float* __restrict__ ob)
{
    int o = blockIdx.x;   // 0..99
    __shared__ float Ms[320];
    __shared__ float red[256];
    for (int idx = threadIdx.x; idx < 320; idx += 256) {
      int a = idx / 5, d = idx - a*5;
      int r = a, c = o*5 + d;
      int mf = r >> 4, kg = (r >> 2) & 3, q = r & 3;
      int ng = c >> 7, wv = (c >> 5) & 3, nf = (c >> 4) & 1, l15 = c & 15;
      int t = wv*64 + kg*16 + l15, j8 = nf*4 + q;
      const float* p = Mpart2 + ((size_t)(ng*32)*4 + mf)*2048 + t*8 + j8;
      float s = 0.f;
      #pragma unroll 8
      for (int kg8 = 0; kg8 < 32; kg8++) s += p[(size_t)kg8*8192];
      Ms[idx] = s;
    }
    __syncthreads();
    int b = threadIdx.x & 63, aq = threadIdx.x >> 6;
    float s = 0.f;
    for (int a = aq*16; a < aq*16+16; a++) {
      float n = 0.f;
      #pragma unroll
      for (int d=0; d<5; d++) n += fabsf(Ms[a*5+d] - Ms[b*5+d]);
      s += expf(-n);
    }
    red[threadIdx.x] = s;
    __syncthreads();
    if (threadIdx.x < 64)
      ob[(size_t)b*100 + o] = red[b] + red[64+b] + red[128+b] + red[192+b];
}

__global__ void k_final2(const double* __restrict__ fpart,
    const float* __restrict__ ob, const float* __restrict__ lw,
    const float* __restrict__ lb, float* __restrict__ out)
{
    int b = threadIdx.x;   // 64 threads, 1 block
    double s = 0.0;
    #pragma unroll
    for (int i = 0; i < 8; i++) s += fpart[b*8 + i];
    for (int o = 0; o < 100; o++)
      s = fma((double)ob[(size_t)b*100 + o], (double)lw[FLAT + o], s);
    s += (double)lb[0];
    out[b] = (float)(1.0 / (1.0 + exp(-s)));
}

extern "C" void kernel_launch(void* const* d_in, const int* in_sizes, int n_in,
                              void* d_out, int out_size, void* d_ws, size_t ws_size,
                              hipStream_t stream)
{
    const float* x   = (const float*)d_in[0];
    const float* w1  = (const float*)d_in[1];
    const float* b1  = (const float*)d_in[2];
    const float* w2  = (const float*)d_in[3];
    const float* b2  = (const float*)d_in[4];
    const float* gam = (const float*)d_in[5];
    const float* bet = (const float*)d_in[6];
    const float* T   = (const float*)d_in[7];
    const float* lw  = (const float*)d_in[8];
    const float* lb  = (const float*)d_in[9];
    float* out = (float*)d_out;

    float* ws = (float*)d_ws;
    // Layout (float offsets), ws ~1GB:
    //   [0 .. 8,388,608)            h1 bf16 -> later Mpart bf16 [1024][8192]
    //   [8,388,608 .. 12,582,912)   h2b bf16 [64][131072]
    //   [12,582,912 .. 12,648,448)  Bw bf16
    //   [12,648,704 .. 12,655,104)  ob (6400 f32)
    //   [12,655,104 .. 13,703,680)  Mpart2 (1,048,576 f32)
    //   [13,703,680 .. 13,834,752)  bnp2 (65,536 doubles: s1 [0,32768), s2 [32768,65536))
    //   [13,834,752 .. +1024)       fpart (512 doubles)
    __hip_bfloat16* h1 = (__hip_bfloat16*)ws;
    __hip_bfloat16* Mpart = (__hip_bfloat16*)ws;      // aliases h1 (dead after conv2)
    __hip_bfloat16* h2b = (__hip_bfloat16*)(ws + 8388608);
    __hip_bfloat16* Bw  = (__hip_bfloat16*)(ws + 12582912);
    float* ob    = ws + 12648704;
    float* Mpart2 = ws + 12655104;
    double* bnp2  = (double*)(ws + 13703680);
    double* fpart = (double*)(ws + 13834752);

    k_conv1p<<<1536, 256, 0, stream>>>(x, w1, b1, w2, h1, Bw);
    k_conv2<<<512, 256, 0, stream>>>(h1, Bw, b2, h2b, bnp2);
    k_mgf<<<1536, 256, 0, stream>>>(h2b, bnp2, gam, bet, T, lw, Mpart, fpart);
    k_mreduceA<<<128, 256, 0, stream>>>(Mpart, Mpart2);
    k_ob<<<100, 256, 0, stream>>>(Mpart2, ob);
    k_final2<<<1, 64, 0, stream>>>(fpart, ob, lw, lb, out);
}